// Round 1
// baseline (708.709 us; speedup 1.0000x reference)
//
#include <hip/hip_runtime.h>
#include <hip/hip_bf16.h>

// ---------------- problem constants (match reference) ----------------
constexpr int N_NODES  = 50000;
constexpr int N_EDGES  = 800000;
constexpr int NE_TOT   = N_EDGES + N_NODES;   // edges + self loops
constexpr int F_HID    = 128;
constexpr int N_GRAPHS = 64;
constexpr float BN_EPS = 1e-5f;

// ---------------- CSR build ----------------
__global__ __launch_bounds__(256) void init_cnt_kernel(int* __restrict__ cnt) {
    int i = blockIdx.x * 256 + threadIdx.x;
    if (i < N_NODES) cnt[i] = 1;   // self loop
}

__global__ __launch_bounds__(256) void count_kernel(const int* __restrict__ ei, int* __restrict__ cnt) {
    int i = blockIdx.x * 256 + threadIdx.x;
    if (i < N_EDGES) atomicAdd(&cnt[ei[N_EDGES + i]], 1);   // dst row
}

// 3-phase exclusive scan over cnt[N_NODES] -> row_ptr
__global__ __launch_bounds__(1024) void scan_blocks_kernel(const int* __restrict__ cnt,
                                                           int* __restrict__ row_ptr,
                                                           int* __restrict__ blockSums) {
    int tid = threadIdx.x;
    int gid = blockIdx.x * 1024 + tid;
    int v = (gid < N_NODES) ? cnt[gid] : 0;
    int lane = tid & 63, wid = tid >> 6;
    int x = v;
#pragma unroll
    for (int off = 1; off < 64; off <<= 1) {
        int y = __shfl_up(x, off);
        if (lane >= off) x += y;
    }
    __shared__ int wsum[16];
    if (lane == 63) wsum[wid] = x;
    __syncthreads();
    if (tid < 16) {
        int w = wsum[tid];
        int xx = w;
#pragma unroll
        for (int off = 1; off < 16; off <<= 1) {
            int y = __shfl_up(xx, off);
            if (tid >= off) xx += y;
        }
        wsum[tid] = xx - w;   // exclusive wave offsets
    }
    __syncthreads();
    int incl = x + wsum[wid];
    if (gid < N_NODES) row_ptr[gid] = incl - v;          // block-local exclusive
    if (tid == 1023) blockSums[blockIdx.x] = incl;       // block total
}

__global__ void scan_totals_kernel(const int* __restrict__ blockSums, int* __restrict__ blockOff,
                                   int* __restrict__ row_ptr, int nb) {
    int lane = threadIdx.x;   // single wave of 64
    int v = (lane < nb) ? blockSums[lane] : 0;
    int x = v;
#pragma unroll
    for (int off = 1; off < 64; off <<= 1) {
        int y = __shfl_up(x, off);
        if (lane >= off) x += y;
    }
    if (lane < nb) blockOff[lane] = x - v;
    if (lane == nb - 1) row_ptr[N_NODES] = x;   // total = E+N
}

__global__ __launch_bounds__(256) void finalize_kernel(int* __restrict__ row_ptr, const int* __restrict__ blockOff,
                                                       const int* __restrict__ cnt, float* __restrict__ dinv,
                                                       int* __restrict__ cursor) {
    int i = blockIdx.x * 256 + threadIdx.x;
    if (i >= N_NODES) return;
    int rp = row_ptr[i] + blockOff[i >> 10];
    row_ptr[i] = rp;
    cursor[i] = rp;
    dinv[i] = rsqrtf((float)cnt[i]);   // deg >= 1 always (self loop)
}

__global__ __launch_bounds__(256) void fill_kernel(const int* __restrict__ ei, const float* __restrict__ dinv,
                                                   int* __restrict__ cursor, int* __restrict__ col_src,
                                                   float* __restrict__ col_norm) {
    int i = blockIdx.x * 256 + threadIdx.x;
    if (i >= NE_TOT) return;
    int s, d;
    if (i < N_EDGES) { s = ei[i]; d = ei[N_EDGES + i]; }
    else             { s = i - N_EDGES; d = s; }
    int pos = atomicAdd(&cursor[d], 1);
    col_src[pos]  = s;
    col_norm[pos] = dinv[s] * dinv[d];
}

// ---------------- dense transform: C[N,128] = A[N,K] @ W[K,128] ----------------
template<int K>
__global__ __launch_bounds__(256) void gemm_kernel(const float* __restrict__ A, const float* __restrict__ W,
                                                   float* __restrict__ C) {
    constexpr int M = 128, BK = 16, BR = 64;
    __shared__ float As[BK][BR + 4];   // transposed [k][row], +4 pad keeps float4 align & breaks bank conflicts
    __shared__ float Bs[BK][M];
    int tid = threadIdx.x;
    int tr = tid & 15;     // rows tr*4 .. tr*4+3
    int tc = tid >> 4;     // cols tc*8 .. tc*8+7
    int row0 = blockIdx.x * BR;
    float acc[4][8] = {};
    for (int k0 = 0; k0 < K; k0 += BK) {
        // stage A tile (64 rows x 16 k), transposed into LDS
        {
            int r  = tid >> 2;
            int kk = (tid & 3) * 4;
            int gr = row0 + r;
            float4 av = make_float4(0.f, 0.f, 0.f, 0.f);
            if (gr < N_NODES) av = *(const float4*)(A + (size_t)gr * K + k0 + kk);
            As[kk + 0][r] = av.x; As[kk + 1][r] = av.y; As[kk + 2][r] = av.z; As[kk + 3][r] = av.w;
        }
        // stage B tile (16 k x 128)
#pragma unroll
        for (int i = 0; i < 2; i++) {
            int f4 = tid + i * 256;
            int bk = f4 >> 5;
            int c  = (f4 & 31) * 4;
            *(float4*)&Bs[bk][c] = *(const float4*)(W + (size_t)(k0 + bk) * M + c);
        }
        __syncthreads();
#pragma unroll
        for (int k = 0; k < BK; k++) {
            float4 a4 = *(const float4*)&As[k][tr * 4];
            float4 b0 = *(const float4*)&Bs[k][tc * 8];
            float4 b1 = *(const float4*)&Bs[k][tc * 8 + 4];
            const float aa[4] = {a4.x, a4.y, a4.z, a4.w};
            const float bb[8] = {b0.x, b0.y, b0.z, b0.w, b1.x, b1.y, b1.z, b1.w};
#pragma unroll
            for (int rr = 0; rr < 4; rr++)
#pragma unroll
                for (int cc = 0; cc < 8; cc++)
                    acc[rr][cc] = fmaf(aa[rr], bb[cc], acc[rr][cc]);
        }
        __syncthreads();
    }
#pragma unroll
    for (int rr = 0; rr < 4; rr++) {
        int gr = row0 + tr * 4 + rr;
        if (gr < N_NODES) {
            float4 o0 = {acc[rr][0], acc[rr][1], acc[rr][2], acc[rr][3]};
            float4 o1 = {acc[rr][4], acc[rr][5], acc[rr][6], acc[rr][7]};
            *(float4*)(C + (size_t)gr * M + tc * 8)     = o0;
            *(float4*)(C + (size_t)gr * M + tc * 8 + 4) = o1;
        }
    }
}

// ---------------- sparse aggregation: one wave per dst node ----------------
__global__ __launch_bounds__(256) void aggregate_kernel(const float* __restrict__ h, const int* __restrict__ row_ptr,
                                                        const int* __restrict__ col_src, const float* __restrict__ col_norm,
                                                        float* __restrict__ outp) {
    int wv   = (blockIdx.x * 256 + threadIdx.x) >> 6;
    int lane = threadIdx.x & 63;
    if (wv >= N_NODES) return;
    int beg = row_ptr[wv], end = row_ptr[wv + 1];
    float ax = 0.f, ay = 0.f;
    int e = beg;
    for (; e + 2 <= end; e += 2) {   // 2-way unroll -> 2 outstanding gathers
        int   s0 = col_src[e],  s1 = col_src[e + 1];
        float w0 = col_norm[e], w1 = col_norm[e + 1];
        float2 v0 = *(const float2*)(h + (size_t)s0 * F_HID + lane * 2);
        float2 v1 = *(const float2*)(h + (size_t)s1 * F_HID + lane * 2);
        ax += w0 * v0.x; ay += w0 * v0.y;
        ax += w1 * v1.x; ay += w1 * v1.y;
    }
    if (e < end) {
        int   s0 = col_src[e];
        float w0 = col_norm[e];
        float2 v0 = *(const float2*)(h + (size_t)s0 * F_HID + lane * 2);
        ax += w0 * v0.x; ay += w0 * v0.y;
    }
    float2 o; o.x = ax; o.y = ay;
    *(float2*)(outp + (size_t)wv * F_HID + lane * 2) = o;
}

// ---------------- BN stats (column sums / sumsq) ----------------
__global__ __launch_bounds__(256) void stats_kernel(const float* __restrict__ h, float* __restrict__ colstats) {
    int col = threadIdx.x & 127, half = threadIdx.x >> 7;
    float s = 0.f, s2 = 0.f;
    for (int n = blockIdx.x * 2 + half; n < N_NODES; n += gridDim.x * 2) {
        float v = h[(size_t)n * F_HID + col];
        s += v; s2 += v * v;
    }
    __shared__ float sh[256], sh2[256];
    sh[threadIdx.x] = s; sh2[threadIdx.x] = s2;
    __syncthreads();
    if (half == 0) {
        atomicAdd(&colstats[col],       sh[col]  + sh[col + 128]);
        atomicAdd(&colstats[128 + col], sh2[col] + sh2[col + 128]);
    }
}

// ---------------- fused BN + ReLU (bias cancels through BN) ----------------
__global__ __launch_bounds__(256) void bn_relu_kernel(float* __restrict__ h, const float* __restrict__ colstats,
                                                      const float* __restrict__ gam, const float* __restrict__ beta) {
    int idx = blockIdx.x * 256 + threadIdx.x;   // one float4
    constexpr int TOT4 = N_NODES * (F_HID / 4);
    if (idx >= TOT4) return;
    int c4 = (idx & 31) * 4;
    constexpr float invN = 1.0f / N_NODES;
    float4 v = ((float4*)h)[idx];
    float* vv = (float*)&v;
#pragma unroll
    for (int i = 0; i < 4; i++) {
        int c = c4 + i;
        float mean = colstats[c] * invN;
        float var  = colstats[128 + c] * invN - mean * mean;
        float sc   = gam[c] * rsqrtf(var + BN_EPS);
        vv[i] = fmaxf((vv[i] - mean) * sc + beta[c], 0.0f);
    }
    ((float4*)h)[idx] = v;
}

// ---------------- pooling ----------------
__global__ void boundaries_kernel(const int* __restrict__ batch, int* __restrict__ start) {
    int g = threadIdx.x;
    if (g > N_GRAPHS) return;
    int lo = 0, hi = N_NODES;
    while (lo < hi) {
        int mid = (lo + hi) >> 1;
        if (batch[mid] < g) lo = mid + 1; else hi = mid;
    }
    start[g] = lo;   // lower_bound; start[64] = N
}

__global__ __launch_bounds__(256) void pool_kernel(const float* __restrict__ h, const int* __restrict__ start,
                                                   float* __restrict__ pooled) {
    int g = blockIdx.x;
    int col = threadIdx.x & 127, half = threadIdx.x >> 7;
    int s = start[g], e = start[g + 1];
    float acc = 0.f;
    for (int n = s + half; n < e; n += 2) acc += h[(size_t)n * F_HID + col];
    __shared__ float sh[256];
    sh[threadIdx.x] = acc;
    __syncthreads();
    if (half == 0) {
        float tot  = sh[col] + sh[col + 128];
        float cntf = (float)(e - s);
        pooled[g * F_HID + col] = tot / fmaxf(cntf, 1.0f);
    }
}

// ---------------- MLP head ----------------
__global__ __launch_bounds__(256) void mlp_kernel(const float* __restrict__ pooled,
                                                  const float* __restrict__ Wf1, const float* __restrict__ bf1,
                                                  const float* __restrict__ Wf2, const float* __restrict__ bf2,
                                                  float* __restrict__ out) {
    __shared__ float p[128];
    __shared__ float h1[256];
    int g = blockIdx.x, t = threadIdx.x;
    if (t < 128) p[t] = pooled[g * F_HID + t];
    __syncthreads();
    float acc = bf1[t];
#pragma unroll 8
    for (int k = 0; k < 128; k++) acc = fmaf(p[k], Wf1[k * 256 + t], acc);
    h1[t] = fmaxf(acc, 0.f);
    __syncthreads();
    if (t < 10) {
        float o = bf2[t];
#pragma unroll 8
        for (int j = 0; j < 256; j++) o = fmaf(h1[j], Wf2[j * 10 + t], o);
        out[g * 10 + t] = o;
    }
}

// ---------------- host launch ----------------
extern "C" void kernel_launch(void* const* d_in, const int* in_sizes, int n_in,
                              void* d_out, int out_size, void* d_ws, size_t ws_size,
                              hipStream_t stream) {
    (void)in_sizes; (void)n_in; (void)out_size; (void)ws_size;
    const float* x     = (const float*)d_in[0];
    const int*   ei    = (const int*)d_in[1];
    const int*   batch = (const int*)d_in[2];
    const float* W1    = (const float*)d_in[3];
    const float* g1    = (const float*)d_in[5];
    const float* beta1 = (const float*)d_in[6];
    const float* W2    = (const float*)d_in[7];
    const float* g2    = (const float*)d_in[9];
    const float* beta2 = (const float*)d_in[10];
    const float* W3    = (const float*)d_in[11];
    const float* g3    = (const float*)d_in[13];
    const float* beta3 = (const float*)d_in[14];
    const float* Wf1   = (const float*)d_in[15];
    const float* bf1   = (const float*)d_in[16];
    const float* Wf2   = (const float*)d_in[17];
    const float* bf2   = (const float*)d_in[18];
    float* out = (float*)d_out;

    char* p = (char*)d_ws;
    auto alloc = [&](size_t bytes) { char* q = p; p += (bytes + 255) & ~(size_t)255; return q; };
    float* bufA      = (float*)alloc((size_t)N_NODES * F_HID * 4);   // transform output h
    float* bufB      = (float*)alloc((size_t)N_NODES * F_HID * 4);   // agg / layer output
    int*   col_src   = (int*)  alloc((size_t)NE_TOT * 4);
    float* col_norm  = (float*)alloc((size_t)NE_TOT * 4);
    int*   cnt       = (int*)  alloc((size_t)N_NODES * 4);
    int*   row_ptr   = (int*)  alloc((size_t)(N_NODES + 1) * 4);
    int*   cursor    = (int*)  alloc((size_t)N_NODES * 4);
    float* dinv      = (float*)alloc((size_t)N_NODES * 4);
    int*   blockSums = (int*)  alloc(64 * 4);
    int*   blockOff  = (int*)  alloc(64 * 4);
    float* colstats  = (float*)alloc(256 * 4);
    int*   start     = (int*)  alloc((N_GRAPHS + 1) * 4);
    float* pooled    = (float*)alloc((size_t)N_GRAPHS * F_HID * 4);

    int nb = (N_NODES + 1023) / 1024;   // 49

    // ---- degree count + CSR build (once per call) ----
    init_cnt_kernel<<<(N_NODES + 255) / 256, 256, 0, stream>>>(cnt);
    count_kernel<<<(N_EDGES + 255) / 256, 256, 0, stream>>>(ei, cnt);
    scan_blocks_kernel<<<nb, 1024, 0, stream>>>(cnt, row_ptr, blockSums);
    scan_totals_kernel<<<1, 64, 0, stream>>>(blockSums, blockOff, row_ptr, nb);
    finalize_kernel<<<(N_NODES + 255) / 256, 256, 0, stream>>>(row_ptr, blockOff, cnt, dinv, cursor);
    fill_kernel<<<(NE_TOT + 255) / 256, 256, 0, stream>>>(ei, dinv, cursor, col_src, col_norm);

    // ---- 3 GCN layers ----
    const float* Ws[3]  = {W1, W2, W3};
    const float* Gs[3]  = {g1, g2, g3};
    const float* Bts[3] = {beta1, beta2, beta3};
    for (int l = 0; l < 3; l++) {
        if (l == 0)
            gemm_kernel<96><<<(N_NODES + 63) / 64, 256, 0, stream>>>(x, Ws[0], bufA);
        else
            gemm_kernel<128><<<(N_NODES + 63) / 64, 256, 0, stream>>>(bufB, Ws[l], bufA);
        aggregate_kernel<<<N_NODES / 4, 256, 0, stream>>>(bufA, row_ptr, col_src, col_norm, bufB);
        hipMemsetAsync(colstats, 0, 256 * sizeof(float), stream);
        stats_kernel<<<256, 256, 0, stream>>>(bufB, colstats);
        bn_relu_kernel<<<(N_NODES * 32 + 255) / 256, 256, 0, stream>>>(bufB, colstats, Gs[l], Bts[l]);
    }

    // ---- pool + MLP head ----
    boundaries_kernel<<<1, 128, 0, stream>>>(batch, start);
    pool_kernel<<<N_GRAPHS, 256, 0, stream>>>(bufB, start, pooled);
    mlp_kernel<<<N_GRAPHS, 256, 0, stream>>>(pooled, Wf1, bf1, Wf2, bf2, out);
}

// Round 3
// 618.227 us; speedup vs baseline: 1.1464x; 1.1464x over previous
//
#include <hip/hip_runtime.h>
#include <hip/hip_bf16.h>

// ---------------- problem constants (match reference) ----------------
constexpr int N_NODES  = 50000;
constexpr int N_EDGES  = 800000;
constexpr int NE_TOT   = N_EDGES + N_NODES;   // edges + self loops
constexpr int F_HID    = 128;
constexpr int N_GRAPHS = 64;
constexpr float BN_EPS = 1e-5f;

// ---------------- CSR build ----------------
__global__ __launch_bounds__(256) void init_cnt_kernel(int* __restrict__ cnt) {
    int i = blockIdx.x * 256 + threadIdx.x;
    if (i < N_NODES) cnt[i] = 1;   // self loop
}

__global__ __launch_bounds__(256) void count_kernel(const int* __restrict__ ei, int* __restrict__ cnt) {
    int i = blockIdx.x * 256 + threadIdx.x;
    if (i < N_EDGES) atomicAdd(&cnt[ei[N_EDGES + i]], 1);   // dst row
}

// 3-phase exclusive scan over cnt[N_NODES] -> row_ptr
__global__ __launch_bounds__(1024) void scan_blocks_kernel(const int* __restrict__ cnt,
                                                           int* __restrict__ row_ptr,
                                                           int* __restrict__ blockSums) {
    int tid = threadIdx.x;
    int gid = blockIdx.x * 1024 + tid;
    int v = (gid < N_NODES) ? cnt[gid] : 0;
    int lane = tid & 63, wid = tid >> 6;
    int x = v;
#pragma unroll
    for (int off = 1; off < 64; off <<= 1) {
        int y = __shfl_up(x, off);
        if (lane >= off) x += y;
    }
    __shared__ int wsum[16];
    if (lane == 63) wsum[wid] = x;
    __syncthreads();
    if (tid < 16) {
        int w = wsum[tid];
        int xx = w;
#pragma unroll
        for (int off = 1; off < 16; off <<= 1) {
            int y = __shfl_up(xx, off);
            if (tid >= off) xx += y;
        }
        wsum[tid] = xx - w;   // exclusive wave offsets
    }
    __syncthreads();
    int incl = x + wsum[wid];
    if (gid < N_NODES) row_ptr[gid] = incl - v;          // block-local exclusive
    if (tid == 1023) blockSums[blockIdx.x] = incl;       // block total
}

__global__ void scan_totals_kernel(const int* __restrict__ blockSums, int* __restrict__ blockOff,
                                   int* __restrict__ row_ptr, int nb) {
    int lane = threadIdx.x;   // single wave of 64
    int v = (lane < nb) ? blockSums[lane] : 0;
    int x = v;
#pragma unroll
    for (int off = 1; off < 64; off <<= 1) {
        int y = __shfl_up(x, off);
        if (lane >= off) x += y;
    }
    if (lane < nb) blockOff[lane] = x - v;
    if (lane == nb - 1) row_ptr[N_NODES] = x;   // total = E+N
}

__global__ __launch_bounds__(256) void finalize_kernel(int* __restrict__ row_ptr, const int* __restrict__ blockOff,
                                                       const int* __restrict__ cnt, float* __restrict__ dinv,
                                                       int* __restrict__ cursor) {
    int i = blockIdx.x * 256 + threadIdx.x;
    if (i >= N_NODES) return;
    int rp = row_ptr[i] + blockOff[i >> 10];
    row_ptr[i] = rp;
    cursor[i] = rp;
    dinv[i] = rsqrtf((float)cnt[i]);   // deg >= 1 always (self loop)
}

__global__ __launch_bounds__(256) void fill_kernel(const int* __restrict__ ei, const float* __restrict__ dinv,
                                                   int* __restrict__ cursor, int* __restrict__ col_src,
                                                   float* __restrict__ col_norm) {
    int i = blockIdx.x * 256 + threadIdx.x;
    if (i >= NE_TOT) return;
    int s, d;
    if (i < N_EDGES) { s = ei[i]; d = ei[N_EDGES + i]; }
    else             { s = i - N_EDGES; d = s; }
    int pos = atomicAdd(&cursor[d], 1);
    col_src[pos]  = s;
    col_norm[pos] = dinv[s] * dinv[d];
}

// ---------------- dense transform: C[N,128] = A[N,K] @ W[K,128] ----------------
template<int K>
__global__ __launch_bounds__(256) void gemm_kernel(const float* __restrict__ A, const float* __restrict__ W,
                                                   float* __restrict__ C) {
    constexpr int M = 128, BK = 16, BR = 64;
    __shared__ float As[BK][BR + 4];
    __shared__ float Bs[BK][M];
    int tid = threadIdx.x;
    int tr = tid & 15;
    int tc = tid >> 4;
    int row0 = blockIdx.x * BR;
    float acc[4][8] = {};
    for (int k0 = 0; k0 < K; k0 += BK) {
        {
            int r  = tid >> 2;
            int kk = (tid & 3) * 4;
            int gr = row0 + r;
            float4 av = make_float4(0.f, 0.f, 0.f, 0.f);
            if (gr < N_NODES) av = *(const float4*)(A + (size_t)gr * K + k0 + kk);
            As[kk + 0][r] = av.x; As[kk + 1][r] = av.y; As[kk + 2][r] = av.z; As[kk + 3][r] = av.w;
        }
#pragma unroll
        for (int i = 0; i < 2; i++) {
            int f4 = tid + i * 256;
            int bk = f4 >> 5;
            int c  = (f4 & 31) * 4;
            *(float4*)&Bs[bk][c] = *(const float4*)(W + (size_t)(k0 + bk) * M + c);
        }
        __syncthreads();
#pragma unroll
        for (int k = 0; k < BK; k++) {
            float4 a4 = *(const float4*)&As[k][tr * 4];
            float4 b0 = *(const float4*)&Bs[k][tc * 8];
            float4 b1 = *(const float4*)&Bs[k][tc * 8 + 4];
            const float aa[4] = {a4.x, a4.y, a4.z, a4.w};
            const float bb[8] = {b0.x, b0.y, b0.z, b0.w, b1.x, b1.y, b1.z, b1.w};
#pragma unroll
            for (int rr = 0; rr < 4; rr++)
#pragma unroll
                for (int cc = 0; cc < 8; cc++)
                    acc[rr][cc] = fmaf(aa[rr], bb[cc], acc[rr][cc]);
        }
        __syncthreads();
    }
#pragma unroll
    for (int rr = 0; rr < 4; rr++) {
        int gr = row0 + tr * 4 + rr;
        if (gr < N_NODES) {
            float4 o0 = {acc[rr][0], acc[rr][1], acc[rr][2], acc[rr][3]};
            float4 o1 = {acc[rr][4], acc[rr][5], acc[rr][6], acc[rr][7]};
            *(float4*)(C + (size_t)gr * M + tc * 8)     = o0;
            *(float4*)(C + (size_t)gr * M + tc * 8 + 4) = o1;
        }
    }
}

// ---------------- sparse aggregation: one wave per dst node ----------------
__global__ __launch_bounds__(256) void aggregate_kernel(const float* __restrict__ h, const int* __restrict__ row_ptr,
                                                        const int* __restrict__ col_src, const float* __restrict__ col_norm,
                                                        float* __restrict__ outp) {
    int wv   = (blockIdx.x * 256 + threadIdx.x) >> 6;
    int lane = threadIdx.x & 63;
    if (wv >= N_NODES) return;
    int beg = row_ptr[wv], end = row_ptr[wv + 1];
    float ax = 0.f, ay = 0.f;
    int e = beg;
    for (; e + 4 <= end; e += 4) {   // 4 outstanding gathers
        int   s0 = col_src[e],  s1 = col_src[e + 1], s2 = col_src[e + 2], s3 = col_src[e + 3];
        float w0 = col_norm[e], w1 = col_norm[e + 1], w2 = col_norm[e + 2], w3 = col_norm[e + 3];
        float2 v0 = *(const float2*)(h + (size_t)s0 * F_HID + lane * 2);
        float2 v1 = *(const float2*)(h + (size_t)s1 * F_HID + lane * 2);
        float2 v2 = *(const float2*)(h + (size_t)s2 * F_HID + lane * 2);
        float2 v3 = *(const float2*)(h + (size_t)s3 * F_HID + lane * 2);
        ax += w0 * v0.x; ay += w0 * v0.y;
        ax += w1 * v1.x; ay += w1 * v1.y;
        ax += w2 * v2.x; ay += w2 * v2.y;
        ax += w3 * v3.x; ay += w3 * v3.y;
    }
    for (; e < end; e++) {
        int   s0 = col_src[e];
        float w0 = col_norm[e];
        float2 v0 = *(const float2*)(h + (size_t)s0 * F_HID + lane * 2);
        ax += w0 * v0.x; ay += w0 * v0.y;
    }
    float2 o; o.x = ax; o.y = ay;
    *(float2*)(outp + (size_t)wv * F_HID + lane * 2) = o;
}

// ---------------- BN stats (column sums / sumsq) ----------------
__global__ __launch_bounds__(256) void stats_kernel(const float* __restrict__ h, float* __restrict__ colstats) {
    int col = threadIdx.x & 127, half = threadIdx.x >> 7;
    float s = 0.f, s2 = 0.f;
    for (int n = blockIdx.x * 2 + half; n < N_NODES; n += gridDim.x * 2) {
        float v = h[(size_t)n * F_HID + col];
        s += v; s2 += v * v;
    }
    __shared__ float sh[256], sh2[256];
    sh[threadIdx.x] = s; sh2[threadIdx.x] = s2;
    __syncthreads();
    if (half == 0) {
        atomicAdd(&colstats[col],       sh[col]  + sh[col + 128]);
        atomicAdd(&colstats[128 + col], sh2[col] + sh2[col + 128]);
    }
}

// ---------------- fused BN + ReLU (bias cancels through BN) ----------------
__global__ __launch_bounds__(256) void bn_relu_kernel(float* __restrict__ h, const float* __restrict__ colstats,
                                                      const float* __restrict__ gam, const float* __restrict__ beta) {
    int idx = blockIdx.x * 256 + threadIdx.x;   // one float4
    constexpr int TOT4 = N_NODES * (F_HID / 4);
    if (idx >= TOT4) return;
    int c4 = (idx & 31) * 4;
    constexpr float invN = 1.0f / N_NODES;
    float4 v = ((float4*)h)[idx];
    float* vv = (float*)&v;
#pragma unroll
    for (int i = 0; i < 4; i++) {
        int c = c4 + i;
        float mean = colstats[c] * invN;
        float var  = colstats[128 + c] * invN - mean * mean;
        float sc   = gam[c] * rsqrtf(var + BN_EPS);
        vv[i] = fmaxf((vv[i] - mean) * sc + beta[c], 0.0f);
    }
    ((float4*)h)[idx] = v;
}

// ---------------- pooling ----------------
__global__ void boundaries_kernel(const int* __restrict__ batch, int* __restrict__ start) {
    int g = threadIdx.x;
    if (g > N_GRAPHS) return;
    int lo = 0, hi = N_NODES;
    while (lo < hi) {
        int mid = (lo + hi) >> 1;
        if (batch[mid] < g) lo = mid + 1; else hi = mid;
    }
    start[g] = lo;   // lower_bound; start[64] = N
}

// phase 1: per-block run-length accumulation, atomic flush per graph-segment
constexpr int POOL_ROWS = 128;
__global__ __launch_bounds__(256) void pool_partial_kernel(const float* __restrict__ h, const int* __restrict__ batch,
                                                           float* __restrict__ pooled_sum) {
    int row0 = blockIdx.x * POOL_ROWS;
    int col = threadIdx.x & 127, half = threadIdx.x >> 7;
    __shared__ int sbatch[POOL_ROWS];
    if (threadIdx.x < POOL_ROWS) {
        int r = row0 + threadIdx.x;
        sbatch[threadIdx.x] = (r < N_NODES) ? batch[r] : -1;
    }
    __syncthreads();
    int nrows = min(POOL_ROWS, N_NODES - row0);
    if (half >= nrows) return;
    int cur = sbatch[half];
    float acc = 0.f;
    for (int r = half; r < nrows; r += 2) {
        int g = sbatch[r];            // wave-uniform across the wave (half is uniform per wave)
        if (g != cur) {
            atomicAdd(&pooled_sum[cur * F_HID + col], acc);
            cur = g; acc = 0.f;
        }
        acc += h[(size_t)(row0 + r) * F_HID + col];
    }
    atomicAdd(&pooled_sum[cur * F_HID + col], acc);
}

// ---------------- MLP head (divide-by-count folded in) ----------------
__global__ __launch_bounds__(256) void mlp_kernel(const float* __restrict__ pooled_sum, const int* __restrict__ start,
                                                  const float* __restrict__ Wf1, const float* __restrict__ bf1,
                                                  const float* __restrict__ Wf2, const float* __restrict__ bf2,
                                                  float* __restrict__ out) {
    __shared__ float p[128];
    __shared__ float h1[256];
    int g = blockIdx.x, t = threadIdx.x;
    if (t < 128) {
        float cnt = (float)(start[g + 1] - start[g]);
        p[t] = pooled_sum[g * F_HID + t] / fmaxf(cnt, 1.0f);
    }
    __syncthreads();
    float acc = bf1[t];
#pragma unroll 8
    for (int k = 0; k < 128; k++) acc = fmaf(p[k], Wf1[k * 256 + t], acc);
    h1[t] = fmaxf(acc, 0.f);
    __syncthreads();
    if (t < 10) {
        float o = bf2[t];
#pragma unroll 8
        for (int j = 0; j < 256; j++) o = fmaf(h1[j], Wf2[j * 10 + t], o);
        out[g * 10 + t] = o;
    }
}

// ---------------- host launch ----------------
extern "C" void kernel_launch(void* const* d_in, const int* in_sizes, int n_in,
                              void* d_out, int out_size, void* d_ws, size_t ws_size,
                              hipStream_t stream) {
    (void)in_sizes; (void)n_in; (void)out_size; (void)ws_size;
    const float* x     = (const float*)d_in[0];
    const int*   ei    = (const int*)d_in[1];
    const int*   batch = (const int*)d_in[2];
    const float* W1    = (const float*)d_in[3];
    const float* g1    = (const float*)d_in[5];
    const float* beta1 = (const float*)d_in[6];
    const float* W2    = (const float*)d_in[7];
    const float* g2    = (const float*)d_in[9];
    const float* beta2 = (const float*)d_in[10];
    const float* W3    = (const float*)d_in[11];
    const float* g3    = (const float*)d_in[13];
    const float* beta3 = (const float*)d_in[14];
    const float* Wf1   = (const float*)d_in[15];
    const float* bf1   = (const float*)d_in[16];
    const float* Wf2   = (const float*)d_in[17];
    const float* bf2   = (const float*)d_in[18];
    float* out = (float*)d_out;

    char* p = (char*)d_ws;
    auto alloc = [&](size_t bytes) { char* q = p; p += (bytes + 255) & ~(size_t)255; return q; };
    float* bufA       = (float*)alloc((size_t)N_NODES * F_HID * 4);
    float* bufB       = (float*)alloc((size_t)N_NODES * F_HID * 4);
    int*   col_src    = (int*)  alloc((size_t)NE_TOT * 4);
    float* col_norm   = (float*)alloc((size_t)NE_TOT * 4);
    int*   cnt        = (int*)  alloc((size_t)N_NODES * 4);
    int*   row_ptr    = (int*)  alloc((size_t)(N_NODES + 1) * 4);
    int*   cursor     = (int*)  alloc((size_t)N_NODES * 4);
    float* dinv       = (float*)alloc((size_t)N_NODES * 4);
    int*   blockSums  = (int*)  alloc(64 * 4);
    int*   blockOff   = (int*)  alloc(64 * 4);
    float* colstats   = (float*)alloc(256 * 4);
    int*   start      = (int*)  alloc((N_GRAPHS + 1) * 4);
    float* pooled_sum = (float*)alloc((size_t)N_GRAPHS * F_HID * 4);

    int nb = (N_NODES + 1023) / 1024;   // 49

    // ---- degree count + CSR build (once per call) ----
    init_cnt_kernel<<<(N_NODES + 255) / 256, 256, 0, stream>>>(cnt);
    count_kernel<<<(N_EDGES + 255) / 256, 256, 0, stream>>>(ei, cnt);
    scan_blocks_kernel<<<nb, 1024, 0, stream>>>(cnt, row_ptr, blockSums);
    scan_totals_kernel<<<1, 64, 0, stream>>>(blockSums, blockOff, row_ptr, nb);
    finalize_kernel<<<(N_NODES + 255) / 256, 256, 0, stream>>>(row_ptr, blockOff, cnt, dinv, cursor);
    fill_kernel<<<(NE_TOT + 255) / 256, 256, 0, stream>>>(ei, dinv, cursor, col_src, col_norm);

    // ---- 3 GCN layers ----
    const float* Ws[3]  = {W1, W2, W3};
    const float* Gs[3]  = {g1, g2, g3};
    const float* Bts[3] = {beta1, beta2, beta3};
    for (int l = 0; l < 3; l++) {
        if (l == 0)
            gemm_kernel<96><<<(N_NODES + 63) / 64, 256, 0, stream>>>(x, Ws[0], bufA);
        else
            gemm_kernel<128><<<(N_NODES + 63) / 64, 256, 0, stream>>>(bufB, Ws[l], bufA);
        aggregate_kernel<<<N_NODES / 4, 256, 0, stream>>>(bufA, row_ptr, col_src, col_norm, bufB);
        hipMemsetAsync(colstats, 0, 256 * sizeof(float), stream);
        stats_kernel<<<1024, 256, 0, stream>>>(bufB, colstats);
        bn_relu_kernel<<<(N_NODES * 32 + 255) / 256, 256, 0, stream>>>(bufB, colstats, Gs[l], Bts[l]);
    }

    // ---- pool + MLP head ----
    boundaries_kernel<<<1, 128, 0, stream>>>(batch, start);
    hipMemsetAsync(pooled_sum, 0, (size_t)N_GRAPHS * F_HID * 4, stream);
    pool_partial_kernel<<<(N_NODES + POOL_ROWS - 1) / POOL_ROWS, 256, 0, stream>>>(bufB, batch, pooled_sum);
    mlp_kernel<<<N_GRAPHS, 256, 0, stream>>>(pooled_sum, start, Wf1, bf1, Wf2, bf2, out);
}

// Round 4
// 522.428 us; speedup vs baseline: 1.3566x; 1.1834x over previous
//
#include <hip/hip_runtime.h>
#include <hip/hip_bf16.h>

// ---------------- problem constants (match reference) ----------------
constexpr int N_NODES  = 50000;
constexpr int N_EDGES  = 800000;
constexpr int NE_TOT   = N_EDGES + N_NODES;   // edges + self loops
constexpr int F_HID    = 128;
constexpr int N_GRAPHS = 64;
constexpr float BN_EPS = 1e-5f;

using short8  = __attribute__((ext_vector_type(8))) short;
using float4v = __attribute__((ext_vector_type(4))) float;

__device__ __forceinline__ ushort f2bf(float f) {
    uint u = __float_as_uint(f);
    return (ushort)((u + 0x7fffu + ((u >> 16) & 1u)) >> 16);   // RNE
}
__device__ __forceinline__ float bf2f(ushort b) {
    return __uint_as_float(((uint)b) << 16);
}

// ---------------- dtype conversions (once per call) ----------------
__global__ __launch_bounds__(256) void conv_x_kernel(const float* __restrict__ x, ushort* __restrict__ xb) {
    int i = blockIdx.x * 256 + threadIdx.x;              // one float4 -> ushort4
    constexpr int TOT4 = N_NODES * 96 / 4;
    if (i >= TOT4) return;
    float4 v = ((const float4*)x)[i];
    ushort4 o = {f2bf(v.x), f2bf(v.y), f2bf(v.z), f2bf(v.w)};
    ((ushort4*)xb)[i] = o;
}

// Wt[n][k] = bf16(W[k][n]);  W is [K][128]
template<int K>
__global__ __launch_bounds__(256) void conv_w_kernel(const float* __restrict__ W, ushort* __restrict__ Wt) {
    int i = blockIdx.x * 256 + threadIdx.x;   // i = k*128 + n
    if (i >= K * 128) return;
    int n = i & 127, k = i >> 7;
    Wt[n * K + k] = f2bf(W[i]);
}

// ---------------- CSR build ----------------
__global__ __launch_bounds__(256) void init_cnt_kernel(int* __restrict__ cnt) {
    int i = blockIdx.x * 256 + threadIdx.x;
    if (i < N_NODES) cnt[i] = 1;   // self loop
}

__global__ __launch_bounds__(256) void count_kernel(const int* __restrict__ ei, int* __restrict__ cnt) {
    int i = blockIdx.x * 256 + threadIdx.x;
    if (i < N_EDGES) atomicAdd(&cnt[ei[N_EDGES + i]], 1);   // dst row
}

// 3-phase exclusive scan over cnt[N_NODES] -> row_ptr
__global__ __launch_bounds__(1024) void scan_blocks_kernel(const int* __restrict__ cnt,
                                                           int* __restrict__ row_ptr,
                                                           int* __restrict__ blockSums) {
    int tid = threadIdx.x;
    int gid = blockIdx.x * 1024 + tid;
    int v = (gid < N_NODES) ? cnt[gid] : 0;
    int lane = tid & 63, wid = tid >> 6;
    int x = v;
#pragma unroll
    for (int off = 1; off < 64; off <<= 1) {
        int y = __shfl_up(x, off);
        if (lane >= off) x += y;
    }
    __shared__ int wsum[16];
    if (lane == 63) wsum[wid] = x;
    __syncthreads();
    if (tid < 16) {
        int w = wsum[tid];
        int xx = w;
#pragma unroll
        for (int off = 1; off < 16; off <<= 1) {
            int y = __shfl_up(xx, off);
            if (tid >= off) xx += y;
        }
        wsum[tid] = xx - w;   // exclusive wave offsets
    }
    __syncthreads();
    int incl = x + wsum[wid];
    if (gid < N_NODES) row_ptr[gid] = incl - v;          // block-local exclusive
    if (tid == 1023) blockSums[blockIdx.x] = incl;       // block total
}

__global__ void scan_totals_kernel(const int* __restrict__ blockSums, int* __restrict__ blockOff,
                                   int* __restrict__ row_ptr, int nb) {
    int lane = threadIdx.x;   // single wave of 64
    int v = (lane < nb) ? blockSums[lane] : 0;
    int x = v;
#pragma unroll
    for (int off = 1; off < 64; off <<= 1) {
        int y = __shfl_up(x, off);
        if (lane >= off) x += y;
    }
    if (lane < nb) blockOff[lane] = x - v;
    if (lane == nb - 1) row_ptr[N_NODES] = x;   // total = E+N
}

__global__ __launch_bounds__(256) void finalize_kernel(int* __restrict__ row_ptr, const int* __restrict__ blockOff,
                                                       const int* __restrict__ cnt, float* __restrict__ dinv,
                                                       int* __restrict__ cursor) {
    int i = blockIdx.x * 256 + threadIdx.x;
    if (i >= N_NODES) return;
    int rp = row_ptr[i] + blockOff[i >> 10];
    row_ptr[i] = rp;
    cursor[i] = rp;
    dinv[i] = rsqrtf((float)cnt[i]);   // deg >= 1 always (self loop)
}

// packed edge record: .x = src index, .y = float bits of norm
__global__ __launch_bounds__(256) void fill_kernel(const int* __restrict__ ei, const float* __restrict__ dinv,
                                                   int* __restrict__ cursor, int2* __restrict__ col) {
    int i = blockIdx.x * 256 + threadIdx.x;
    if (i >= NE_TOT) return;
    int s, d;
    if (i < N_EDGES) { s = ei[i]; d = ei[N_EDGES + i]; }
    else             { s = i - N_EDGES; d = s; }
    int pos = atomicAdd(&cursor[d], 1);
    int2 rec; rec.x = s; rec.y = __float_as_int(dinv[s] * dinv[d]);
    col[pos] = rec;   // single 8B scattered store
}

// ---------------- MFMA dense transform: C[N,128] = A[N,K] @ W[K,128], all bf16 in, bf16 out ----------------
// A row-major bf16 [N][K]; Wt transposed bf16 [128][K]
template<int K>
__global__ __launch_bounds__(256) void mfma_gemm_kernel(const ushort* __restrict__ A, const ushort* __restrict__ Wt,
                                                        ushort* __restrict__ C) {
    constexpr int KSTEPS = K / 32;
    int wave = threadIdx.x >> 6, lane = threadIdx.x & 63;
    int m = lane & 15, quad = lane >> 4;
    int row_base = blockIdx.x * 64 + wave * 16;

    // preload A fragments: A[m=lane&15][k = quad*8 + j + kstep*32]
    short8 afrag[KSTEPS];
    int arow = row_base + m;
    if (arow >= N_NODES) arow = N_NODES - 1;   // clamp; stores are guarded
#pragma unroll
    for (int ks = 0; ks < KSTEPS; ks++)
        afrag[ks] = *(const short8*)(A + (size_t)arow * K + ks * 32 + quad * 8);

#pragma unroll
    for (int nt = 0; nt < 8; nt++) {
        float4v acc = {0.f, 0.f, 0.f, 0.f};
        const ushort* wbase = Wt + (size_t)(nt * 16 + m) * K + quad * 8;   // B: n=lane&15, k=quad*8+j
#pragma unroll
        for (int ks = 0; ks < KSTEPS; ks++) {
            short8 bfrag = *(const short8*)(wbase + ks * 32);
            acc = __builtin_amdgcn_mfma_f32_16x16x32_bf16(afrag[ks], bfrag, acc, 0, 0, 0);
        }
        // C/D: col = lane&15, row = quad*4 + reg
        int colg = nt * 16 + m;
#pragma unroll
        for (int r = 0; r < 4; r++) {
            int rowg = row_base + quad * 4 + r;
            if (rowg < N_NODES) C[(size_t)rowg * F_HID + colg] = f2bf(acc[r]);
        }
    }
}

// ---------------- sparse aggregation: one wave per dst node, bf16 gather, f32 out ----------------
__global__ __launch_bounds__(256) void aggregate_kernel(const ushort* __restrict__ h, const int* __restrict__ row_ptr,
                                                        const int2* __restrict__ col, float* __restrict__ outp) {
    int wv   = (blockIdx.x * 256 + threadIdx.x) >> 6;
    int lane = threadIdx.x & 63;
    if (wv >= N_NODES) return;
    int beg = row_ptr[wv], end = row_ptr[wv + 1];
    float ax = 0.f, ay = 0.f;
    int e = beg;
    for (; e + 4 <= end; e += 4) {   // 4 outstanding gathers
        int4 e01 = *(const int4*)&col[e];
        int4 e23 = *(const int4*)&col[e + 2];
        uint u0 = *(const uint*)(h + (size_t)e01.x * F_HID + lane * 2);
        uint u1 = *(const uint*)(h + (size_t)e01.z * F_HID + lane * 2);
        uint u2 = *(const uint*)(h + (size_t)e23.x * F_HID + lane * 2);
        uint u3 = *(const uint*)(h + (size_t)e23.z * F_HID + lane * 2);
        float w0 = __int_as_float(e01.y), w1 = __int_as_float(e01.w);
        float w2 = __int_as_float(e23.y), w3 = __int_as_float(e23.w);
        ax += w0 * __uint_as_float(u0 << 16); ay += w0 * __uint_as_float(u0 & 0xffff0000u);
        ax += w1 * __uint_as_float(u1 << 16); ay += w1 * __uint_as_float(u1 & 0xffff0000u);
        ax += w2 * __uint_as_float(u2 << 16); ay += w2 * __uint_as_float(u2 & 0xffff0000u);
        ax += w3 * __uint_as_float(u3 << 16); ay += w3 * __uint_as_float(u3 & 0xffff0000u);
    }
    for (; e < end; e++) {
        int2 rec = col[e];
        uint u = *(const uint*)(h + (size_t)rec.x * F_HID + lane * 2);
        float w = __int_as_float(rec.y);
        ax += w * __uint_as_float(u << 16); ay += w * __uint_as_float(u & 0xffff0000u);
    }
    float2 o; o.x = ax; o.y = ay;
    *(float2*)(outp + (size_t)wv * F_HID + lane * 2) = o;
}

// ---------------- BN stats (column sums / sumsq over f32 agg) ----------------
__global__ __launch_bounds__(256) void stats_kernel(const float* __restrict__ h, float* __restrict__ colstats) {
    int col = threadIdx.x & 127, half = threadIdx.x >> 7;
    float s = 0.f, s2 = 0.f;
    for (int n = blockIdx.x * 2 + half; n < N_NODES; n += gridDim.x * 2) {
        float v = h[(size_t)n * F_HID + col];
        s += v; s2 += v * v;
    }
    __shared__ float sh[256], sh2[256];
    sh[threadIdx.x] = s; sh2[threadIdx.x] = s2;
    __syncthreads();
    if (half == 0) {
        atomicAdd(&colstats[col],       sh[col]  + sh[col + 128]);
        atomicAdd(&colstats[128 + col], sh2[col] + sh2[col + 128]);
    }
}

// ---------------- fused BN + ReLU, f32 in -> bf16 out (bias cancels through BN) ----------------
__global__ __launch_bounds__(256) void bn_relu_kernel(const float* __restrict__ h, const float* __restrict__ colstats,
                                                      const float* __restrict__ gam, const float* __restrict__ beta,
                                                      ushort* __restrict__ outb) {
    int idx = blockIdx.x * 256 + threadIdx.x;   // one float4 / ushort4
    constexpr int TOT4 = N_NODES * (F_HID / 4);
    if (idx >= TOT4) return;
    int c4 = (idx & 31) * 4;
    constexpr float invN = 1.0f / N_NODES;
    float4 v = ((const float4*)h)[idx];
    float* vv = (float*)&v;
    ushort4 o;
    ushort* oo = (ushort*)&o;
#pragma unroll
    for (int i = 0; i < 4; i++) {
        int c = c4 + i;
        float mean = colstats[c] * invN;
        float var  = colstats[128 + c] * invN - mean * mean;
        float sc   = gam[c] * rsqrtf(var + BN_EPS);
        oo[i] = f2bf(fmaxf((vv[i] - mean) * sc + beta[c], 0.0f));
    }
    ((ushort4*)outb)[idx] = o;
}

// ---------------- pooling ----------------
__global__ void boundaries_kernel(const int* __restrict__ batch, int* __restrict__ start) {
    int g = threadIdx.x;
    if (g > N_GRAPHS) return;
    int lo = 0, hi = N_NODES;
    while (lo < hi) {
        int mid = (lo + hi) >> 1;
        if (batch[mid] < g) lo = mid + 1; else hi = mid;
    }
    start[g] = lo;   // lower_bound; start[64] = N
}

// per-block run-length accumulation over bf16 h, atomic flush per graph-segment
constexpr int POOL_ROWS = 128;
__global__ __launch_bounds__(256) void pool_partial_kernel(const ushort* __restrict__ h, const int* __restrict__ batch,
                                                           float* __restrict__ pooled_sum) {
    int row0 = blockIdx.x * POOL_ROWS;
    int col = threadIdx.x & 127, half = threadIdx.x >> 7;
    __shared__ int sbatch[POOL_ROWS];
    if (threadIdx.x < POOL_ROWS) {
        int r = row0 + threadIdx.x;
        sbatch[threadIdx.x] = (r < N_NODES) ? batch[r] : -1;
    }
    __syncthreads();
    int nrows = min(POOL_ROWS, N_NODES - row0);
    if (half >= nrows) return;
    int cur = sbatch[half];
    float acc = 0.f;
    for (int r = half; r < nrows; r += 2) {
        int g = sbatch[r];            // wave-uniform (half is uniform per wave)
        if (g != cur) {
            atomicAdd(&pooled_sum[cur * F_HID + col], acc);
            cur = g; acc = 0.f;
        }
        acc += bf2f(h[(size_t)(row0 + r) * F_HID + col]);
    }
    atomicAdd(&pooled_sum[cur * F_HID + col], acc);
}

// ---------------- MLP head (divide-by-count folded in, f32) ----------------
__global__ __launch_bounds__(256) void mlp_kernel(const float* __restrict__ pooled_sum, const int* __restrict__ start,
                                                  const float* __restrict__ Wf1, const float* __restrict__ bf1,
                                                  const float* __restrict__ Wf2, const float* __restrict__ bf2,
                                                  float* __restrict__ out) {
    __shared__ float p[128];
    __shared__ float h1[256];
    int g = blockIdx.x, t = threadIdx.x;
    if (t < 128) {
        float cnt = (float)(start[g + 1] - start[g]);
        p[t] = pooled_sum[g * F_HID + t] / fmaxf(cnt, 1.0f);
    }
    __syncthreads();
    float acc = bf1[t];
#pragma unroll 8
    for (int k = 0; k < 128; k++) acc = fmaf(p[k], Wf1[k * 256 + t], acc);
    h1[t] = fmaxf(acc, 0.f);
    __syncthreads();
    if (t < 10) {
        float o = bf2[t];
#pragma unroll 8
        for (int j = 0; j < 256; j++) o = fmaf(h1[j], Wf2[j * 10 + t], o);
        out[g * 10 + t] = o;
    }
}

// ---------------- host launch ----------------
extern "C" void kernel_launch(void* const* d_in, const int* in_sizes, int n_in,
                              void* d_out, int out_size, void* d_ws, size_t ws_size,
                              hipStream_t stream) {
    (void)in_sizes; (void)n_in; (void)out_size; (void)ws_size;
    const float* x     = (const float*)d_in[0];
    const int*   ei    = (const int*)d_in[1];
    const int*   batch = (const int*)d_in[2];
    const float* W1    = (const float*)d_in[3];
    const float* g1    = (const float*)d_in[5];
    const float* beta1 = (const float*)d_in[6];
    const float* W2    = (const float*)d_in[7];
    const float* g2    = (const float*)d_in[9];
    const float* beta2 = (const float*)d_in[10];
    const float* W3    = (const float*)d_in[11];
    const float* g3    = (const float*)d_in[13];
    const float* beta3 = (const float*)d_in[14];
    const float* Wf1   = (const float*)d_in[15];
    const float* bf1   = (const float*)d_in[16];
    const float* Wf2   = (const float*)d_in[17];
    const float* bf2   = (const float*)d_in[18];
    float* out = (float*)d_out;

    char* p = (char*)d_ws;
    auto alloc = [&](size_t bytes) { char* q = p; p += (bytes + 255) & ~(size_t)255; return q; };
    ushort* xb        = (ushort*)alloc((size_t)N_NODES * 96 * 2);      // bf16 x
    ushort* hbA       = (ushort*)alloc((size_t)N_NODES * F_HID * 2);   // bf16 gemm out
    ushort* hbB       = (ushort*)alloc((size_t)N_NODES * F_HID * 2);   // bf16 layer out
    float*  bufF      = (float*) alloc((size_t)N_NODES * F_HID * 4);   // f32 agg out
    int2*   col       = (int2*)  alloc((size_t)NE_TOT * 8);            // packed (src, norm)
    ushort* W1t       = (ushort*)alloc((size_t)96  * 128 * 2);
    ushort* W2t       = (ushort*)alloc((size_t)128 * 128 * 2);
    ushort* W3t       = (ushort*)alloc((size_t)128 * 128 * 2);
    int*    cnt       = (int*)   alloc((size_t)N_NODES * 4);
    int*    row_ptr   = (int*)   alloc((size_t)(N_NODES + 1) * 4);
    int*    cursor    = (int*)   alloc((size_t)N_NODES * 4);
    float*  dinv      = (float*) alloc((size_t)N_NODES * 4);
    int*    blockSums = (int*)   alloc(64 * 4);
    int*    blockOff  = (int*)   alloc(64 * 4);
    float*  colstats  = (float*) alloc(256 * 4);
    int*    start     = (int*)   alloc((N_GRAPHS + 1) * 4);
    float*  pooled_sum= (float*) alloc((size_t)N_GRAPHS * F_HID * 4);

    int nb = (N_NODES + 1023) / 1024;   // 49

    // ---- dtype conversions ----
    conv_x_kernel<<<(N_NODES * 96 / 4 + 255) / 256, 256, 0, stream>>>(x, xb);
    conv_w_kernel<96> <<<(96  * 128 + 255) / 256, 256, 0, stream>>>(W1, W1t);
    conv_w_kernel<128><<<(128 * 128 + 255) / 256, 256, 0, stream>>>(W2, W2t);
    conv_w_kernel<128><<<(128 * 128 + 255) / 256, 256, 0, stream>>>(W3, W3t);

    // ---- degree count + CSR build (once per call) ----
    init_cnt_kernel<<<(N_NODES + 255) / 256, 256, 0, stream>>>(cnt);
    count_kernel<<<(N_EDGES + 255) / 256, 256, 0, stream>>>(ei, cnt);
    scan_blocks_kernel<<<nb, 1024, 0, stream>>>(cnt, row_ptr, blockSums);
    scan_totals_kernel<<<1, 64, 0, stream>>>(blockSums, blockOff, row_ptr, nb);
    finalize_kernel<<<(N_NODES + 255) / 256, 256, 0, stream>>>(row_ptr, blockOff, cnt, dinv, cursor);
    fill_kernel<<<(NE_TOT + 255) / 256, 256, 0, stream>>>(ei, dinv, cursor, col);

    // ---- 3 GCN layers ----
    const float* Gs[3]  = {g1, g2, g3};
    const float* Bts[3] = {beta1, beta2, beta3};
    int gemm_grid = (N_NODES + 63) / 64;   // 782
    for (int l = 0; l < 3; l++) {
        if (l == 0)
            mfma_gemm_kernel<96><<<gemm_grid, 256, 0, stream>>>(xb, W1t, hbA);
        else
            mfma_gemm_kernel<128><<<gemm_grid, 256, 0, stream>>>(hbB, (l == 1) ? W2t : W3t, hbA);
        aggregate_kernel<<<N_NODES / 4, 256, 0, stream>>>(hbA, row_ptr, col, bufF);
        hipMemsetAsync(colstats, 0, 256 * sizeof(float), stream);
        stats_kernel<<<1024, 256, 0, stream>>>(bufF, colstats);
        bn_relu_kernel<<<(N_NODES * 32 + 255) / 256, 256, 0, stream>>>(bufF, colstats, Gs[l], Bts[l], hbB);
    }

    // ---- pool + MLP head ----
    boundaries_kernel<<<1, 128, 0, stream>>>(batch, start);
    hipMemsetAsync(pooled_sum, 0, (size_t)N_GRAPHS * F_HID * 4, stream);
    pool_partial_kernel<<<(N_NODES + POOL_ROWS - 1) / POOL_ROWS, 256, 0, stream>>>(hbB, batch, pooled_sum);
    mlp_kernel<<<N_GRAPHS, 256, 0, stream>>>(pooled_sum, start, Wf1, bf1, Wf2, bf2, out);
}

// Round 5
// 489.863 us; speedup vs baseline: 1.4467x; 1.0665x over previous
//
#include <hip/hip_runtime.h>
#include <hip/hip_bf16.h>
#include <hip/hip_fp16.h>

// ---------------- problem constants (match reference) ----------------
constexpr int N_NODES  = 50000;
constexpr int N_EDGES  = 800000;
constexpr int NE_TOT   = N_EDGES + N_NODES;   // edges + self loops
constexpr int F_HID    = 128;
constexpr int N_GRAPHS = 64;
constexpr float BN_EPS = 1e-5f;

using short8  = __attribute__((ext_vector_type(8))) short;
using float4v = __attribute__((ext_vector_type(4))) float;

__device__ __forceinline__ ushort f2bf(float f) {
    uint u = __float_as_uint(f);
    return (ushort)((u + 0x7fffu + ((u >> 16) & 1u)) >> 16);   // RNE
}
__device__ __forceinline__ float bf2f(ushort b) {
    return __uint_as_float(((uint)b) << 16);
}
__device__ __forceinline__ float bflo(uint u) { return __uint_as_float(u << 16); }
__device__ __forceinline__ float bfhi(uint u) { return __uint_as_float(u & 0xffff0000u); }

// ---------------- dtype conversions (once per call) ----------------
__global__ __launch_bounds__(256) void conv_x_kernel(const float* __restrict__ x, ushort* __restrict__ xb) {
    int i = blockIdx.x * 256 + threadIdx.x;              // one float4 -> ushort4
    constexpr int TOT4 = N_NODES * 96 / 4;
    if (i >= TOT4) return;
    float4 v = ((const float4*)x)[i];
    ushort4 o = {f2bf(v.x), f2bf(v.y), f2bf(v.z), f2bf(v.w)};
    ((ushort4*)xb)[i] = o;
}

// all three weights, transposed to [n][k] bf16, one kernel
__global__ __launch_bounds__(256) void conv_w_kernel(const float* __restrict__ W1, const float* __restrict__ W2,
                                                     const float* __restrict__ W3, ushort* __restrict__ W1t,
                                                     ushort* __restrict__ W2t, ushort* __restrict__ W3t) {
    int i = blockIdx.x * 256 + threadIdx.x;
    constexpr int S1 = 96 * 128, S2 = S1 + 128 * 128, S3 = S2 + 128 * 128;
    if (i < S1) {
        int n = i & 127, k = i >> 7;
        W1t[n * 96 + k] = f2bf(W1[i]);
    } else if (i < S2) {
        int j = i - S1, n = j & 127, k = j >> 7;
        W2t[n * 128 + k] = f2bf(W2[j]);
    } else if (i < S3) {
        int j = i - S2, n = j & 127, k = j >> 7;
        W3t[n * 128 + k] = f2bf(W3[j]);
    }
}

// ---------------- CSR build ----------------
__global__ __launch_bounds__(256) void init_cnt_kernel(int* __restrict__ cnt) {
    int i = blockIdx.x * 256 + threadIdx.x;
    if (i < N_NODES) cnt[i] = 1;   // self loop
}

__global__ __launch_bounds__(256) void count_kernel(const int* __restrict__ ei, int* __restrict__ cnt) {
    int i = blockIdx.x * 256 + threadIdx.x;
    if (i < N_EDGES) atomicAdd(&cnt[ei[N_EDGES + i]], 1);   // dst row
}

// 3-phase exclusive scan over cnt[N_NODES] -> row_ptr
__global__ __launch_bounds__(1024) void scan_blocks_kernel(const int* __restrict__ cnt,
                                                           int* __restrict__ row_ptr,
                                                           int* __restrict__ blockSums) {
    int tid = threadIdx.x;
    int gid = blockIdx.x * 1024 + tid;
    int v = (gid < N_NODES) ? cnt[gid] : 0;
    int lane = tid & 63, wid = tid >> 6;
    int x = v;
#pragma unroll
    for (int off = 1; off < 64; off <<= 1) {
        int y = __shfl_up(x, off);
        if (lane >= off) x += y;
    }
    __shared__ int wsum[16];
    if (lane == 63) wsum[wid] = x;
    __syncthreads();
    if (tid < 16) {
        int w = wsum[tid];
        int xx = w;
#pragma unroll
        for (int off = 1; off < 16; off <<= 1) {
            int y = __shfl_up(xx, off);
            if (tid >= off) xx += y;
        }
        wsum[tid] = xx - w;   // exclusive wave offsets
    }
    __syncthreads();
    int incl = x + wsum[wid];
    if (gid < N_NODES) row_ptr[gid] = incl - v;          // block-local exclusive
    if (tid == 1023) blockSums[blockIdx.x] = incl;       // block total
}

__global__ void scan_totals_kernel(const int* __restrict__ blockSums, int* __restrict__ blockOff,
                                   int* __restrict__ row_ptr, int nb) {
    int lane = threadIdx.x;   // single wave of 64
    int v = (lane < nb) ? blockSums[lane] : 0;
    int x = v;
#pragma unroll
    for (int off = 1; off < 64; off <<= 1) {
        int y = __shfl_up(x, off);
        if (lane >= off) x += y;
    }
    if (lane < nb) blockOff[lane] = x - v;
    if (lane == nb - 1) row_ptr[N_NODES] = x;   // total = E+N
}

__global__ __launch_bounds__(256) void finalize_kernel(int* __restrict__ row_ptr, const int* __restrict__ blockOff,
                                                       const int* __restrict__ cnt, float* __restrict__ dinv,
                                                       int* __restrict__ cursor) {
    int i = blockIdx.x * 256 + threadIdx.x;
    if (i >= N_NODES) return;
    int rp = row_ptr[i] + blockOff[i >> 10];
    row_ptr[i] = rp;
    cursor[i] = rp;
    dinv[i] = rsqrtf((float)cnt[i]);   // deg >= 1 always (self loop)
}

// packed edge record: low16 = src index (N<65536), high16 = fp16 bits of norm
__global__ __launch_bounds__(256) void fill_kernel(const int* __restrict__ ei, const float* __restrict__ dinv,
                                                   int* __restrict__ cursor, uint* __restrict__ col) {
    int i = blockIdx.x * 256 + threadIdx.x;
    if (i >= NE_TOT) return;
    int s, d;
    if (i < N_EDGES) { s = ei[i]; d = ei[N_EDGES + i]; }
    else             { s = i - N_EDGES; d = s; }
    int pos = atomicAdd(&cursor[d], 1);
    float nrm = dinv[s] * dinv[d];
    uint h16 = (uint)__half_as_ushort(__float2half(nrm));
    col[pos] = (h16 << 16) | (uint)s;   // single 4B scattered store
}

// ---------------- MFMA dense transform (layer 1): C[N,128] = A[N,96] @ W, bf16 ----------------
template<int K>
__global__ __launch_bounds__(256) void mfma_gemm_kernel(const ushort* __restrict__ A, const ushort* __restrict__ Wt,
                                                        ushort* __restrict__ C) {
    constexpr int KSTEPS = K / 32;
    int wave = threadIdx.x >> 6, lane = threadIdx.x & 63;
    int m = lane & 15, quad = lane >> 4;
    int row_base = blockIdx.x * 64 + wave * 16;

    short8 afrag[KSTEPS];
    int arow = min(row_base + m, N_NODES - 1);   // clamp; stores guarded
#pragma unroll
    for (int ks = 0; ks < KSTEPS; ks++)
        afrag[ks] = *(const short8*)(A + (size_t)arow * K + ks * 32 + quad * 8);

#pragma unroll
    for (int nt = 0; nt < 8; nt++) {
        float4v acc = {0.f, 0.f, 0.f, 0.f};
        const ushort* wbase = Wt + (size_t)(nt * 16 + m) * K + quad * 8;
#pragma unroll
        for (int ks = 0; ks < KSTEPS; ks++) {
            short8 bfrag = *(const short8*)(wbase + ks * 32);
            acc = __builtin_amdgcn_mfma_f32_16x16x32_bf16(afrag[ks], bfrag, acc, 0, 0, 0);
        }
        int colg = nt * 16 + m;
#pragma unroll
        for (int r = 0; r < 4; r++) {
            int rowg = row_base + quad * 4 + r;
            if (rowg < N_NODES) C[(size_t)rowg * F_HID + colg] = f2bf(acc[r]);
        }
    }
}

// ---------------- MFMA transform with fused BN+ReLU on A (layers 2,3) ----------------
// A = f32 aggregate of previous layer; BN applied per input col k, then bf16, then matmul.
__global__ __launch_bounds__(256) void mfma_gemm_bn_kernel(const float* __restrict__ A, const float* __restrict__ cs,
                                                           const float* __restrict__ gam, const float* __restrict__ bet,
                                                           const ushort* __restrict__ Wt, ushort* __restrict__ C) {
    constexpr int K = 128, KSTEPS = 4;
    int wave = threadIdx.x >> 6, lane = threadIdx.x & 63;
    int m = lane & 15, quad = lane >> 4;
    int row_base = blockIdx.x * 64 + wave * 16;
    int arow = min(row_base + m, N_NODES - 1);
    constexpr float invN = 1.0f / N_NODES;

    short8 afrag[KSTEPS];
#pragma unroll
    for (int ks = 0; ks < KSTEPS; ks++) {
        int k0 = ks * 32 + quad * 8;
#pragma unroll
        for (int jj = 0; jj < 8; jj += 4) {
            float4 av = *(const float4*)(A + (size_t)arow * K + k0 + jj);
            float4 sv = *(const float4*)(cs + k0 + jj);
            float4 qv = *(const float4*)(cs + 128 + k0 + jj);
            float4 gv = *(const float4*)(gam + k0 + jj);
            float4 bv = *(const float4*)(bet + k0 + jj);
            const float* a = (const float*)&av; const float* s = (const float*)&sv;
            const float* q = (const float*)&qv; const float* g = (const float*)&gv;
            const float* b = (const float*)&bv;
#pragma unroll
            for (int t = 0; t < 4; t++) {
                float mean = s[t] * invN;
                float var  = q[t] * invN - mean * mean;
                float sc   = g[t] * rsqrtf(var + BN_EPS);
                float val  = fmaxf((a[t] - mean) * sc + b[t], 0.0f);
                afrag[ks][jj + t] = (short)f2bf(val);
            }
        }
    }

#pragma unroll
    for (int nt = 0; nt < 8; nt++) {
        float4v acc = {0.f, 0.f, 0.f, 0.f};
        const ushort* wbase = Wt + (size_t)(nt * 16 + m) * K + quad * 8;
#pragma unroll
        for (int ks = 0; ks < KSTEPS; ks++) {
            short8 bfrag = *(const short8*)(wbase + ks * 32);
            acc = __builtin_amdgcn_mfma_f32_16x16x32_bf16(afrag[ks], bfrag, acc, 0, 0, 0);
        }
        int colg = nt * 16 + m;
#pragma unroll
        for (int r = 0; r < 4; r++) {
            int rowg = row_base + quad * 4 + r;
            if (rowg < N_NODES) C[(size_t)rowg * F_HID + colg] = f2bf(acc[r]);
        }
    }
}

// ---------------- sparse aggregation: one wave per dst row, 2 edges per wave-load ----------------
__global__ __launch_bounds__(256) void aggregate_kernel(const ushort* __restrict__ h, const int* __restrict__ row_ptr,
                                                        const uint* __restrict__ col, float* __restrict__ outp) {
    int wv   = (blockIdx.x * 256 + threadIdx.x) >> 6;
    int lane = threadIdx.x & 63;
    if (wv >= N_NODES) return;
    int half = lane >> 5, sl = lane & 31;   // half-wave serves one edge; lane covers cols sl*4..+3
    int beg = row_ptr[wv], end = row_ptr[wv + 1];
    float a0 = 0.f, a1 = 0.f, a2 = 0.f, a3 = 0.f;
    int base = beg;
    for (; base + 8 <= end; base += 8) {   // 8 edges per iteration, 4 loads in flight per lane
        uint r0 = col[base + 0 + half];
        uint r1 = col[base + 2 + half];
        uint r2 = col[base + 4 + half];
        uint r3 = col[base + 6 + half];
        uint2 v0 = *(const uint2*)(h + (size_t)(r0 & 0xFFFFu) * F_HID + sl * 4);
        uint2 v1 = *(const uint2*)(h + (size_t)(r1 & 0xFFFFu) * F_HID + sl * 4);
        uint2 v2 = *(const uint2*)(h + (size_t)(r2 & 0xFFFFu) * F_HID + sl * 4);
        uint2 v3 = *(const uint2*)(h + (size_t)(r3 & 0xFFFFu) * F_HID + sl * 4);
        float w0 = __half2float(__ushort_as_half((ushort)(r0 >> 16)));
        float w1 = __half2float(__ushort_as_half((ushort)(r1 >> 16)));
        float w2 = __half2float(__ushort_as_half((ushort)(r2 >> 16)));
        float w3 = __half2float(__ushort_as_half((ushort)(r3 >> 16)));
        a0 += w0 * bflo(v0.x); a1 += w0 * bfhi(v0.x); a2 += w0 * bflo(v0.y); a3 += w0 * bfhi(v0.y);
        a0 += w1 * bflo(v1.x); a1 += w1 * bfhi(v1.x); a2 += w1 * bflo(v1.y); a3 += w1 * bfhi(v1.y);
        a0 += w2 * bflo(v2.x); a1 += w2 * bfhi(v2.x); a2 += w2 * bflo(v2.y); a3 += w2 * bfhi(v2.y);
        a0 += w3 * bflo(v3.x); a1 += w3 * bfhi(v3.x); a2 += w3 * bflo(v3.y); a3 += w3 * bfhi(v3.y);
    }
    for (int ee = base + half; ee < end; ee += 2) {   // remainder, halves interleave
        uint r = col[ee];
        uint2 v = *(const uint2*)(h + (size_t)(r & 0xFFFFu) * F_HID + sl * 4);
        float w = __half2float(__ushort_as_half((ushort)(r >> 16)));
        a0 += w * bflo(v.x); a1 += w * bfhi(v.x); a2 += w * bflo(v.y); a3 += w * bfhi(v.y);
    }
    // combine the two halves
    a0 += __shfl_down(a0, 32);
    a1 += __shfl_down(a1, 32);
    a2 += __shfl_down(a2, 32);
    a3 += __shfl_down(a3, 32);
    if (half == 0) {
        float4 o = {a0, a1, a2, a3};
        *(float4*)(outp + (size_t)wv * F_HID + sl * 4) = o;
    }
}

// ---------------- BN stats (column sums / sumsq over f32 agg), float4 loads ----------------
__global__ __launch_bounds__(256) void stats_kernel(const float* __restrict__ h, float* __restrict__ colstats) {
    int c4 = (threadIdx.x & 31) * 4;
    int stripe = threadIdx.x >> 5;   // 0..7
    float s0 = 0, s1 = 0, s2 = 0, s3 = 0, q0 = 0, q1 = 0, q2 = 0, q3 = 0;
    for (int n = blockIdx.x * 8 + stripe; n < N_NODES; n += gridDim.x * 8) {
        float4 v = *(const float4*)(h + (size_t)n * F_HID + c4);
        s0 += v.x; s1 += v.y; s2 += v.z; s3 += v.w;
        q0 += v.x * v.x; q1 += v.y * v.y; q2 += v.z * v.z; q3 += v.w * v.w;
    }
    __shared__ float sh[8][256];
    sh[0][threadIdx.x] = s0; sh[1][threadIdx.x] = s1; sh[2][threadIdx.x] = s2; sh[3][threadIdx.x] = s3;
    sh[4][threadIdx.x] = q0; sh[5][threadIdx.x] = q1; sh[6][threadIdx.x] = q2; sh[7][threadIdx.x] = q3;
    __syncthreads();
    if (stripe == 0) {   // threads 0..31 flush
        int t = threadIdx.x;
#pragma unroll
        for (int c = 0; c < 4; c++) {
            float ts = 0, tq = 0;
#pragma unroll
            for (int k = 0; k < 8; k++) { ts += sh[c][k * 32 + t]; tq += sh[4 + c][k * 32 + t]; }
            atomicAdd(&colstats[c4 + c],       ts);
            atomicAdd(&colstats[128 + c4 + c], tq);
        }
    }
}

// ---------------- fused BN + ReLU for layer 3, f32 in -> bf16 out ----------------
__global__ __launch_bounds__(256) void bn_relu_kernel(const float* __restrict__ h, const float* __restrict__ colstats,
                                                      const float* __restrict__ gam, const float* __restrict__ beta,
                                                      ushort* __restrict__ outb) {
    int idx = blockIdx.x * 256 + threadIdx.x;   // one float4 / ushort4
    constexpr int TOT4 = N_NODES * (F_HID / 4);
    if (idx >= TOT4) return;
    int c4 = (idx & 31) * 4;
    constexpr float invN = 1.0f / N_NODES;
    float4 v = ((const float4*)h)[idx];
    float* vv = (float*)&v;
    ushort4 o;
    ushort* oo = (ushort*)&o;
#pragma unroll
    for (int i = 0; i < 4; i++) {
        int c = c4 + i;
        float mean = colstats[c] * invN;
        float var  = colstats[128 + c] * invN - mean * mean;
        float sc   = gam[c] * rsqrtf(var + BN_EPS);
        oo[i] = f2bf(fmaxf((vv[i] - mean) * sc + beta[c], 0.0f));
    }
    ((ushort4*)outb)[idx] = o;
}

// ---------------- pooling: run-length accumulation, ushort4 loads ----------------
constexpr int POOL_ROWS = 128;
__global__ __launch_bounds__(256) void pool_partial_kernel(const ushort* __restrict__ h, const int* __restrict__ batch,
                                                           float* __restrict__ pooled_sum) {
    int row0 = blockIdx.x * POOL_ROWS;
    int c4 = (threadIdx.x & 31) * 4;
    int stripe = threadIdx.x >> 5;   // 0..7
    __shared__ int sbatch[POOL_ROWS];
    if (threadIdx.x < POOL_ROWS) {
        int r = row0 + threadIdx.x;
        sbatch[threadIdx.x] = (r < N_NODES) ? batch[r] : -1;
    }
    __syncthreads();
    int nrows = min(POOL_ROWS, N_NODES - row0);
    if (stripe >= nrows) return;
    int cur = sbatch[stripe];
    float a0 = 0, a1 = 0, a2 = 0, a3 = 0;
    for (int r = stripe; r < nrows; r += 8) {
        int g = sbatch[r];
        if (g != cur) {
            atomicAdd(&pooled_sum[cur * F_HID + c4 + 0], a0);
            atomicAdd(&pooled_sum[cur * F_HID + c4 + 1], a1);
            atomicAdd(&pooled_sum[cur * F_HID + c4 + 2], a2);
            atomicAdd(&pooled_sum[cur * F_HID + c4 + 3], a3);
            cur = g; a0 = a1 = a2 = a3 = 0.f;
        }
        ushort4 v = *(const ushort4*)(h + (size_t)(row0 + r) * F_HID + c4);
        a0 += bf2f(v.x); a1 += bf2f(v.y); a2 += bf2f(v.z); a3 += bf2f(v.w);
    }
    atomicAdd(&pooled_sum[cur * F_HID + c4 + 0], a0);
    atomicAdd(&pooled_sum[cur * F_HID + c4 + 1], a1);
    atomicAdd(&pooled_sum[cur * F_HID + c4 + 2], a2);
    atomicAdd(&pooled_sum[cur * F_HID + c4 + 3], a3);
}

// ---------------- MLP head (boundary search + divide-by-count folded in) ----------------
__global__ __launch_bounds__(256) void mlp_kernel(const float* __restrict__ pooled_sum, const int* __restrict__ batch,
                                                  const float* __restrict__ Wf1, const float* __restrict__ bf1,
                                                  const float* __restrict__ Wf2, const float* __restrict__ bf2,
                                                  float* __restrict__ out) {
    __shared__ float p[128];
    __shared__ float h1[256];
    __shared__ int se[2];
    int g = blockIdx.x, t = threadIdx.x;
    if (t < 2) {   // lower_bound(batch, g + t)
        int target = g + t;
        int lo = 0, hi = N_NODES;
        while (lo < hi) {
            int mid = (lo + hi) >> 1;
            if (batch[mid] < target) lo = mid + 1; else hi = mid;
        }
        se[t] = lo;
    }
    __syncthreads();
    if (t < 128) {
        float cnt = (float)(se[1] - se[0]);
        p[t] = pooled_sum[g * F_HID + t] / fmaxf(cnt, 1.0f);
    }
    __syncthreads();
    float acc = bf1[t];
#pragma unroll 8
    for (int k = 0; k < 128; k++) acc = fmaf(p[k], Wf1[k * 256 + t], acc);
    h1[t] = fmaxf(acc, 0.f);
    __syncthreads();
    if (t < 10) {
        float o = bf2[t];
#pragma unroll 8
        for (int j = 0; j < 256; j++) o = fmaf(h1[j], Wf2[j * 10 + t], o);
        out[g * 10 + t] = o;
    }
}

// ---------------- host launch ----------------
extern "C" void kernel_launch(void* const* d_in, const int* in_sizes, int n_in,
                              void* d_out, int out_size, void* d_ws, size_t ws_size,
                              hipStream_t stream) {
    (void)in_sizes; (void)n_in; (void)out_size; (void)ws_size;
    const float* x     = (const float*)d_in[0];
    const int*   ei    = (const int*)d_in[1];
    const int*   batch = (const int*)d_in[2];
    const float* W1    = (const float*)d_in[3];
    const float* g1    = (const float*)d_in[5];
    const float* beta1 = (const float*)d_in[6];
    const float* W2    = (const float*)d_in[7];
    const float* g2    = (const float*)d_in[9];
    const float* beta2 = (const float*)d_in[10];
    const float* W3    = (const float*)d_in[11];
    const float* g3    = (const float*)d_in[13];
    const float* beta3 = (const float*)d_in[14];
    const float* Wf1   = (const float*)d_in[15];
    const float* bf1   = (const float*)d_in[16];
    const float* Wf2   = (const float*)d_in[17];
    const float* bf2   = (const float*)d_in[18];
    float* out = (float*)d_out;

    char* p = (char*)d_ws;
    auto alloc = [&](size_t bytes) { char* q = p; p += (bytes + 255) & ~(size_t)255; return q; };
    ushort* xb        = (ushort*)alloc((size_t)N_NODES * 96 * 2);      // bf16 x
    ushort* hbA       = (ushort*)alloc((size_t)N_NODES * F_HID * 2);   // bf16 gemm out
    ushort* hbB       = (ushort*)alloc((size_t)N_NODES * F_HID * 2);   // bf16 layer-3 out
    float*  bufF      = (float*) alloc((size_t)N_NODES * F_HID * 4);   // f32 agg out
    uint*   col       = (uint*)  alloc((size_t)NE_TOT * 4);            // packed (f16 norm | u16 src)
    ushort* W1t       = (ushort*)alloc((size_t)96  * 128 * 2);
    ushort* W2t       = (ushort*)alloc((size_t)128 * 128 * 2);
    ushort* W3t       = (ushort*)alloc((size_t)128 * 128 * 2);
    int*    cnt       = (int*)   alloc((size_t)N_NODES * 4);
    int*    row_ptr   = (int*)   alloc((size_t)(N_NODES + 1) * 4);
    int*    cursor    = (int*)   alloc((size_t)N_NODES * 4);
    float*  dinv      = (float*) alloc((size_t)N_NODES * 4);
    int*    blockSums = (int*)   alloc(64 * 4);
    int*    blockOff  = (int*)   alloc(64 * 4);
    // colstats (3 layers) + pooled_sum contiguous -> single memset
    float*  colstats  = (float*) alloc(3 * 256 * 4);                   // 3072 B, 256-aligned
    float*  pooled_sum= (float*) alloc((size_t)N_GRAPHS * F_HID * 4);  // 32768 B

    int nb = (N_NODES + 1023) / 1024;   // 49

    // ---- dtype conversions ----
    conv_x_kernel<<<(N_NODES * 96 / 4 + 255) / 256, 256, 0, stream>>>(x, xb);
    conv_w_kernel<<<(96 * 128 + 2 * 128 * 128 + 255) / 256, 256, 0, stream>>>(W1, W2, W3, W1t, W2t, W3t);

    // ---- degree count + CSR build (once per call) ----
    init_cnt_kernel<<<(N_NODES + 255) / 256, 256, 0, stream>>>(cnt);
    count_kernel<<<(N_EDGES + 255) / 256, 256, 0, stream>>>(ei, cnt);
    scan_blocks_kernel<<<nb, 1024, 0, stream>>>(cnt, row_ptr, blockSums);
    scan_totals_kernel<<<1, 64, 0, stream>>>(blockSums, blockOff, row_ptr, nb);
    finalize_kernel<<<(N_NODES + 255) / 256, 256, 0, stream>>>(row_ptr, blockOff, cnt, dinv, cursor);
    fill_kernel<<<(NE_TOT + 255) / 256, 256, 0, stream>>>(ei, dinv, cursor, col);

    // one memset for all stat/pool accumulators
    hipMemsetAsync(colstats, 0, 3 * 256 * 4 + (size_t)N_GRAPHS * F_HID * 4, stream);

    // ---- 3 GCN layers (BN+ReLU of layers 1,2 fused into GEMMs 2,3) ----
    int gemm_grid = (N_NODES + 63) / 64;   // 782
    // layer 1
    mfma_gemm_kernel<96><<<gemm_grid, 256, 0, stream>>>(xb, W1t, hbA);
    aggregate_kernel<<<N_NODES / 4, 256, 0, stream>>>(hbA, row_ptr, col, bufF);
    stats_kernel<<<256, 256, 0, stream>>>(bufF, colstats);
    // layer 2
    mfma_gemm_bn_kernel<<<gemm_grid, 256, 0, stream>>>(bufF, colstats, g1, beta1, W2t, hbA);
    aggregate_kernel<<<N_NODES / 4, 256, 0, stream>>>(hbA, row_ptr, col, bufF);
    stats_kernel<<<256, 256, 0, stream>>>(bufF, colstats + 256);
    // layer 3
    mfma_gemm_bn_kernel<<<gemm_grid, 256, 0, stream>>>(bufF, colstats + 256, g2, beta2, W3t, hbA);
    aggregate_kernel<<<N_NODES / 4, 256, 0, stream>>>(hbA, row_ptr, col, bufF);
    stats_kernel<<<256, 256, 0, stream>>>(bufF, colstats + 512);
    bn_relu_kernel<<<(N_NODES * 32 + 255) / 256, 256, 0, stream>>>(bufF, colstats + 512, g3, beta3, hbB);

    // ---- pool + MLP head ----
    pool_partial_kernel<<<(N_NODES + POOL_ROWS - 1) / POOL_ROWS, 256, 0, stream>>>(hbB, batch, pooled_sum);
    mlp_kernel<<<N_GRAPHS, 256, 0, stream>>>(pooled_sum, batch, Wf1, bf1, Wf2, bf2, out);
}

// Round 6
// 453.297 us; speedup vs baseline: 1.5635x; 1.0807x over previous
//
#include <hip/hip_runtime.h>
#include <hip/hip_bf16.h>
#include <hip/hip_fp16.h>

// ---------------- problem constants (match reference) ----------------
constexpr int N_NODES  = 50000;
constexpr int N_EDGES  = 800000;
constexpr int NE_TOT   = N_EDGES + N_NODES;   // edges + self loops
constexpr int COL_MAX  = NE_TOT + 7 * N_NODES; // worst-case padded CSR records
constexpr int F_HID    = 128;
constexpr int N_GRAPHS = 64;
constexpr float BN_EPS = 1e-5f;

using short8  = __attribute__((ext_vector_type(8))) short;
using float4v = __attribute__((ext_vector_type(4))) float;

__device__ __forceinline__ ushort f2bf(float f) {
    uint u = __float_as_uint(f);
    return (ushort)((u + 0x7fffu + ((u >> 16) & 1u)) >> 16);   // RNE
}
__device__ __forceinline__ float bflo(uint u) { return __uint_as_float(u << 16); }
__device__ __forceinline__ float bfhi(uint u) { return __uint_as_float(u & 0xffff0000u); }

// ---------------- merged prep: conv_x | conv_w(all 3) | degree count ----------------
constexpr int CONVX_BLOCKS = (N_NODES * 96 / 4 + 255) / 256;           // 4688
constexpr int CONVW_ELEMS  = 96 * 128 + 2 * 128 * 128;                 // 45056
constexpr int CONVW_BLOCKS = (CONVW_ELEMS + 255) / 256;                // 176
constexpr int COUNT_BLOCKS = (N_EDGES + 255) / 256;                    // 3125
constexpr int PREP_BLOCKS  = CONVX_BLOCKS + CONVW_BLOCKS + COUNT_BLOCKS;

__global__ __launch_bounds__(256) void prep_kernel(const float* __restrict__ x, const int* __restrict__ ei,
                                                   const float* __restrict__ W1, const float* __restrict__ W2,
                                                   const float* __restrict__ W3, ushort* __restrict__ xb,
                                                   ushort* __restrict__ W1t, ushort* __restrict__ W2t,
                                                   ushort* __restrict__ W3t, int* __restrict__ cnt) {
    int b = blockIdx.x;
    if (b < CONVX_BLOCKS) {
        int i = b * 256 + threadIdx.x;
        constexpr int TOT4 = N_NODES * 96 / 4;
        if (i >= TOT4) return;
        float4 v = ((const float4*)x)[i];
        ushort4 o = {f2bf(v.x), f2bf(v.y), f2bf(v.z), f2bf(v.w)};
        ((ushort4*)xb)[i] = o;
    } else if (b < CONVX_BLOCKS + CONVW_BLOCKS) {
        int i = (b - CONVX_BLOCKS) * 256 + threadIdx.x;
        constexpr int S1 = 96 * 128, S2 = S1 + 128 * 128, S3 = S2 + 128 * 128;
        if (i < S1) {
            int n = i & 127, k = i >> 7;
            W1t[n * 96 + k] = f2bf(W1[i]);
        } else if (i < S2) {
            int j = i - S1, n = j & 127, k = j >> 7;
            W2t[n * 128 + k] = f2bf(W2[j]);
        } else if (i < S3) {
            int j = i - S2, n = j & 127, k = j >> 7;
            W3t[n * 128 + k] = f2bf(W3[j]);
        }
    } else {
        int i = (b - CONVX_BLOCKS - CONVW_BLOCKS) * 256 + threadIdx.x;
        if (i < N_EDGES) atomicAdd(&cnt[ei[N_EDGES + i]], 1);   // dst in-degree (cnt pre-zeroed)
    }
}

// ---------------- 3-phase exclusive scan over padded row lengths -> row_ptr ----------------
// row length = pad8(cnt[i] + 1)   (+1 self loop, padded to multiple of 8)
__global__ __launch_bounds__(1024) void scan_blocks_kernel(const int* __restrict__ cnt,
                                                           int* __restrict__ row_ptr,
                                                           int* __restrict__ blockSums) {
    int tid = threadIdx.x;
    int gid = blockIdx.x * 1024 + tid;
    int v = (gid < N_NODES) ? ((cnt[gid] + 8) & ~7) : 0;
    int lane = tid & 63, wid = tid >> 6;
    int x = v;
#pragma unroll
    for (int off = 1; off < 64; off <<= 1) {
        int y = __shfl_up(x, off);
        if (lane >= off) x += y;
    }
    __shared__ int wsum[16];
    if (lane == 63) wsum[wid] = x;
    __syncthreads();
    if (tid < 16) {
        int w = wsum[tid];
        int xx = w;
#pragma unroll
        for (int off = 1; off < 16; off <<= 1) {
            int y = __shfl_up(xx, off);
            if (tid >= off) xx += y;
        }
        wsum[tid] = xx - w;
    }
    __syncthreads();
    int incl = x + wsum[wid];
    if (gid < N_NODES) row_ptr[gid] = incl - v;
    if (tid == 1023) blockSums[blockIdx.x] = incl;
}

__global__ void scan_totals_kernel(const int* __restrict__ blockSums, int* __restrict__ blockOff,
                                   int* __restrict__ row_ptr, int nb) {
    int lane = threadIdx.x;   // single wave
    int v = (lane < nb) ? blockSums[lane] : 0;
    int x = v;
#pragma unroll
    for (int off = 1; off < 64; off <<= 1) {
        int y = __shfl_up(x, off);
        if (lane >= off) x += y;
    }
    if (lane < nb) blockOff[lane] = x - v;
    if (lane == nb - 1) row_ptr[N_NODES] = x;
}

__global__ __launch_bounds__(256) void finalize_kernel(int* __restrict__ row_ptr, const int* __restrict__ blockOff,
                                                       const int* __restrict__ cnt, float* __restrict__ dinv,
                                                       int* __restrict__ cursor) {
    int i = blockIdx.x * 256 + threadIdx.x;
    if (i >= N_NODES) return;
    int rp = row_ptr[i] + blockOff[i >> 10];
    row_ptr[i] = rp;
    cursor[i] = rp;
    dinv[i] = rsqrtf((float)(cnt[i] + 1));   // degree incl self loop
}

// ---------------- merged fill | layer-1 MFMA GEMM ----------------
constexpr int GEMM1_BLOCKS = (N_NODES + 63) / 64;       // 782
constexpr int FILL_BLOCKS  = (NE_TOT + 255) / 256;      // 3321

__global__ __launch_bounds__(256) void fillgemm_kernel(const int* __restrict__ ei, const float* __restrict__ dinv,
                                                       int* __restrict__ cursor, uint* __restrict__ col,
                                                       const ushort* __restrict__ A, const ushort* __restrict__ Wt,
                                                       ushort* __restrict__ C) {
    if (blockIdx.x < GEMM1_BLOCKS) {
        // ---- layer-1 GEMM: C[N,128] = A[N,96] @ W ----
        constexpr int K = 96, KSTEPS = 3;
        int wave = threadIdx.x >> 6, lane = threadIdx.x & 63;
        int m = lane & 15, quad = lane >> 4;
        int row_base = blockIdx.x * 64 + wave * 16;
        short8 afrag[KSTEPS];
        int arow = min(row_base + m, N_NODES - 1);
#pragma unroll
        for (int ks = 0; ks < KSTEPS; ks++)
            afrag[ks] = *(const short8*)(A + (size_t)arow * K + ks * 32 + quad * 8);
#pragma unroll
        for (int nt = 0; nt < 8; nt++) {
            float4v acc = {0.f, 0.f, 0.f, 0.f};
            const ushort* wbase = Wt + (size_t)(nt * 16 + m) * K + quad * 8;
#pragma unroll
            for (int ks = 0; ks < KSTEPS; ks++) {
                short8 bfrag = *(const short8*)(wbase + ks * 32);
                acc = __builtin_amdgcn_mfma_f32_16x16x32_bf16(afrag[ks], bfrag, acc, 0, 0, 0);
            }
            int colg = nt * 16 + m;
#pragma unroll
            for (int r = 0; r < 4; r++) {
                int rowg = row_base + quad * 4 + r;
                if (rowg < N_NODES) C[(size_t)rowg * F_HID + colg] = f2bf(acc[r]);
            }
        }
    } else {
        // ---- CSR fill: packed record (fp16 norm | u16 src) ----
        int i = (blockIdx.x - GEMM1_BLOCKS) * 256 + threadIdx.x;
        if (i >= NE_TOT) return;
        int s, d;
        if (i < N_EDGES) { s = ei[i]; d = ei[N_EDGES + i]; }
        else             { s = i - N_EDGES; d = s; }
        int pos = atomicAdd(&cursor[d], 1);
        float nrm = dinv[s] * dinv[d];
        uint h16 = (uint)__half_as_ushort(__float2half(nrm));
        col[pos] = (h16 << 16) | (uint)s;
    }
}

// ---------------- MFMA transform with fused BN+ReLU on A (layers 2,3) ----------------
__global__ __launch_bounds__(256) void mfma_gemm_bn_kernel(const float* __restrict__ A, const float* __restrict__ cs,
                                                           const float* __restrict__ gam, const float* __restrict__ bet,
                                                           const ushort* __restrict__ Wt, ushort* __restrict__ C) {
    constexpr int K = 128, KSTEPS = 4;
    int wave = threadIdx.x >> 6, lane = threadIdx.x & 63;
    int m = lane & 15, quad = lane >> 4;
    int row_base = blockIdx.x * 64 + wave * 16;
    int arow = min(row_base + m, N_NODES - 1);
    constexpr float invN = 1.0f / N_NODES;

    short8 afrag[KSTEPS];
#pragma unroll
    for (int ks = 0; ks < KSTEPS; ks++) {
        int k0 = ks * 32 + quad * 8;
#pragma unroll
        for (int jj = 0; jj < 8; jj += 4) {
            float4 av = *(const float4*)(A + (size_t)arow * K + k0 + jj);
            float4 sv = *(const float4*)(cs + k0 + jj);
            float4 qv = *(const float4*)(cs + 128 + k0 + jj);
            float4 gv = *(const float4*)(gam + k0 + jj);
            float4 bv = *(const float4*)(bet + k0 + jj);
            const float* a = (const float*)&av; const float* s = (const float*)&sv;
            const float* q = (const float*)&qv; const float* g = (const float*)&gv;
            const float* b = (const float*)&bv;
#pragma unroll
            for (int t = 0; t < 4; t++) {
                float mean = s[t] * invN;
                float var  = q[t] * invN - mean * mean;
                float sc   = g[t] * rsqrtf(var + BN_EPS);
                float val  = fmaxf((a[t] - mean) * sc + b[t], 0.0f);
                afrag[ks][jj + t] = (short)f2bf(val);
            }
        }
    }

#pragma unroll
    for (int nt = 0; nt < 8; nt++) {
        float4v acc = {0.f, 0.f, 0.f, 0.f};
        const ushort* wbase = Wt + (size_t)(nt * 16 + m) * K + quad * 8;
#pragma unroll
        for (int ks = 0; ks < KSTEPS; ks++) {
            short8 bfrag = *(const short8*)(wbase + ks * 32);
            acc = __builtin_amdgcn_mfma_f32_16x16x32_bf16(afrag[ks], bfrag, acc, 0, 0, 0);
        }
        int colg = nt * 16 + m;
#pragma unroll
        for (int r = 0; r < 4; r++) {
            int rowg = row_base + quad * 4 + r;
            if (rowg < N_NODES) C[(size_t)rowg * F_HID + colg] = f2bf(acc[r]);
        }
    }
}

// ---------------- sparse aggregation: one wave per dst row, padded rows (x8) ----------------
__global__ __launch_bounds__(256) void aggregate_kernel(const ushort* __restrict__ h, const int* __restrict__ row_ptr,
                                                        const uint* __restrict__ col, float* __restrict__ outp) {
    int wv   = (blockIdx.x * 256 + threadIdx.x) >> 6;
    int lane = threadIdx.x & 63;
    if (wv >= N_NODES) return;
    int half = lane >> 5, sl = lane & 31;   // half-wave serves one edge; lane covers cols sl*4..+3
    int beg = row_ptr[wv], end = row_ptr[wv + 1];   // length is a multiple of 8; pads have w=0,src=0
    float a0 = 0.f, a1 = 0.f, a2 = 0.f, a3 = 0.f;
    int base = beg;
    for (; base + 16 <= end; base += 16) {   // 16 edges, 8 gathers in flight per lane
        uint r0 = col[base + 0 + half];
        uint r1 = col[base + 2 + half];
        uint r2 = col[base + 4 + half];
        uint r3 = col[base + 6 + half];
        uint r4 = col[base + 8 + half];
        uint r5 = col[base + 10 + half];
        uint r6 = col[base + 12 + half];
        uint r7 = col[base + 14 + half];
        uint2 v0 = *(const uint2*)(h + (size_t)(r0 & 0xFFFFu) * F_HID + sl * 4);
        uint2 v1 = *(const uint2*)(h + (size_t)(r1 & 0xFFFFu) * F_HID + sl * 4);
        uint2 v2 = *(const uint2*)(h + (size_t)(r2 & 0xFFFFu) * F_HID + sl * 4);
        uint2 v3 = *(const uint2*)(h + (size_t)(r3 & 0xFFFFu) * F_HID + sl * 4);
        uint2 v4 = *(const uint2*)(h + (size_t)(r4 & 0xFFFFu) * F_HID + sl * 4);
        uint2 v5 = *(const uint2*)(h + (size_t)(r5 & 0xFFFFu) * F_HID + sl * 4);
        uint2 v6 = *(const uint2*)(h + (size_t)(r6 & 0xFFFFu) * F_HID + sl * 4);
        uint2 v7 = *(const uint2*)(h + (size_t)(r7 & 0xFFFFu) * F_HID + sl * 4);
        float w0 = __half2float(__ushort_as_half((ushort)(r0 >> 16)));
        float w1 = __half2float(__ushort_as_half((ushort)(r1 >> 16)));
        float w2 = __half2float(__ushort_as_half((ushort)(r2 >> 16)));
        float w3 = __half2float(__ushort_as_half((ushort)(r3 >> 16)));
        float w4 = __half2float(__ushort_as_half((ushort)(r4 >> 16)));
        float w5 = __half2float(__ushort_as_half((ushort)(r5 >> 16)));
        float w6 = __half2float(__ushort_as_half((ushort)(r6 >> 16)));
        float w7 = __half2float(__ushort_as_half((ushort)(r7 >> 16)));
        a0 += w0 * bflo(v0.x); a1 += w0 * bfhi(v0.x); a2 += w0 * bflo(v0.y); a3 += w0 * bfhi(v0.y);
        a0 += w1 * bflo(v1.x); a1 += w1 * bfhi(v1.x); a2 += w1 * bflo(v1.y); a3 += w1 * bfhi(v1.y);
        a0 += w2 * bflo(v2.x); a1 += w2 * bfhi(v2.x); a2 += w2 * bflo(v2.y); a3 += w2 * bfhi(v2.y);
        a0 += w3 * bflo(v3.x); a1 += w3 * bfhi(v3.x); a2 += w3 * bflo(v3.y); a3 += w3 * bfhi(v3.y);
        a0 += w4 * bflo(v4.x); a1 += w4 * bfhi(v4.x); a2 += w4 * bflo(v4.y); a3 += w4 * bfhi(v4.y);
        a0 += w5 * bflo(v5.x); a1 += w5 * bfhi(v5.x); a2 += w5 * bflo(v5.y); a3 += w5 * bfhi(v5.y);
        a0 += w6 * bflo(v6.x); a1 += w6 * bfhi(v6.x); a2 += w6 * bflo(v6.y); a3 += w6 * bfhi(v6.y);
        a0 += w7 * bflo(v7.x); a1 += w7 * bfhi(v7.x); a2 += w7 * bflo(v7.y); a3 += w7 * bfhi(v7.y);
    }
    if (base < end) {   // exactly 8 remain (row length % 8 == 0)
        uint r0 = col[base + 0 + half];
        uint r1 = col[base + 2 + half];
        uint r2 = col[base + 4 + half];
        uint r3 = col[base + 6 + half];
        uint2 v0 = *(const uint2*)(h + (size_t)(r0 & 0xFFFFu) * F_HID + sl * 4);
        uint2 v1 = *(const uint2*)(h + (size_t)(r1 & 0xFFFFu) * F_HID + sl * 4);
        uint2 v2 = *(const uint2*)(h + (size_t)(r2 & 0xFFFFu) * F_HID + sl * 4);
        uint2 v3 = *(const uint2*)(h + (size_t)(r3 & 0xFFFFu) * F_HID + sl * 4);
        float w0 = __half2float(__ushort_as_half((ushort)(r0 >> 16)));
        float w1 = __half2float(__ushort_as_half((ushort)(r1 >> 16)));
        float w2 = __half2float(__ushort_as_half((ushort)(r2 >> 16)));
        float w3 = __half2float(__ushort_as_half((ushort)(r3 >> 16)));
        a0 += w0 * bflo(v0.x); a1 += w0 * bfhi(v0.x); a2 += w0 * bflo(v0.y); a3 += w0 * bfhi(v0.y);
        a0 += w1 * bflo(v1.x); a1 += w1 * bfhi(v1.x); a2 += w1 * bflo(v1.y); a3 += w1 * bfhi(v1.y);
        a0 += w2 * bflo(v2.x); a1 += w2 * bfhi(v2.x); a2 += w2 * bflo(v2.y); a3 += w2 * bfhi(v2.y);
        a0 += w3 * bflo(v3.x); a1 += w3 * bfhi(v3.x); a2 += w3 * bflo(v3.y); a3 += w3 * bfhi(v3.y);
    }
    a0 += __shfl_down(a0, 32);
    a1 += __shfl_down(a1, 32);
    a2 += __shfl_down(a2, 32);
    a3 += __shfl_down(a3, 32);
    if (half == 0) {
        float4 o = {a0, a1, a2, a3};
        *(float4*)(outp + (size_t)wv * F_HID + sl * 4) = o;
    }
}

// ---------------- BN stats (column sums / sumsq over f32 agg), float4 loads ----------------
__global__ __launch_bounds__(256) void stats_kernel(const float* __restrict__ h, float* __restrict__ colstats) {
    int c4 = (threadIdx.x & 31) * 4;
    int stripe = threadIdx.x >> 5;   // 0..7
    float s0 = 0, s1 = 0, s2 = 0, s3 = 0, q0 = 0, q1 = 0, q2 = 0, q3 = 0;
    for (int n = blockIdx.x * 8 + stripe; n < N_NODES; n += gridDim.x * 8) {
        float4 v = *(const float4*)(h + (size_t)n * F_HID + c4);
        s0 += v.x; s1 += v.y; s2 += v.z; s3 += v.w;
        q0 += v.x * v.x; q1 += v.y * v.y; q2 += v.z * v.z; q3 += v.w * v.w;
    }
    __shared__ float sh[8][256];
    sh[0][threadIdx.x] = s0; sh[1][threadIdx.x] = s1; sh[2][threadIdx.x] = s2; sh[3][threadIdx.x] = s3;
    sh[4][threadIdx.x] = q0; sh[5][threadIdx.x] = q1; sh[6][threadIdx.x] = q2; sh[7][threadIdx.x] = q3;
    __syncthreads();
    if (stripe == 0) {
        int t = threadIdx.x;
#pragma unroll
        for (int c = 0; c < 4; c++) {
            float ts = 0, tq = 0;
#pragma unroll
            for (int k = 0; k < 8; k++) { ts += sh[c][k * 32 + t]; tq += sh[4 + c][k * 32 + t]; }
            atomicAdd(&colstats[c4 + c],       ts);
            atomicAdd(&colstats[128 + c4 + c], tq);
        }
    }
}

// ---------------- fused layer-3 BN+ReLU + graph pooling ----------------
constexpr int POOL_ROWS = 128;
__global__ __launch_bounds__(256) void pool_bn_kernel(const float* __restrict__ h, const float* __restrict__ cs,
                                                      const float* __restrict__ gam, const float* __restrict__ bet,
                                                      const int* __restrict__ batch, float* __restrict__ pooled_sum) {
    int row0 = blockIdx.x * POOL_ROWS;
    int c4 = (threadIdx.x & 31) * 4;
    int stripe = threadIdx.x >> 5;   // 0..7
    __shared__ int sbatch[POOL_ROWS];
    if (threadIdx.x < POOL_ROWS) {
        int r = row0 + threadIdx.x;
        sbatch[threadIdx.x] = (r < N_NODES) ? batch[r] : -1;
    }
    __syncthreads();
    int nrows = min(POOL_ROWS, N_NODES - row0);
    if (stripe >= nrows) return;
    // BN params for this thread's 4 columns
    constexpr float invN = 1.0f / N_NODES;
    float mean[4], scl[4], bb[4];
#pragma unroll
    for (int t = 0; t < 4; t++) {
        float mn = cs[c4 + t] * invN;
        float var = cs[128 + c4 + t] * invN - mn * mn;
        mean[t] = mn;
        scl[t] = gam[c4 + t] * rsqrtf(var + BN_EPS);
        bb[t] = bet[c4 + t];
    }
    int cur = sbatch[stripe];
    float a0 = 0, a1 = 0, a2 = 0, a3 = 0;
    for (int r = stripe; r < nrows; r += 8) {
        int g = sbatch[r];
        if (g != cur) {
            atomicAdd(&pooled_sum[cur * F_HID + c4 + 0], a0);
            atomicAdd(&pooled_sum[cur * F_HID + c4 + 1], a1);
            atomicAdd(&pooled_sum[cur * F_HID + c4 + 2], a2);
            atomicAdd(&pooled_sum[cur * F_HID + c4 + 3], a3);
            cur = g; a0 = a1 = a2 = a3 = 0.f;
        }
        float4 v = *(const float4*)(h + (size_t)(row0 + r) * F_HID + c4);
        a0 += fmaxf((v.x - mean[0]) * scl[0] + bb[0], 0.f);
        a1 += fmaxf((v.y - mean[1]) * scl[1] + bb[1], 0.f);
        a2 += fmaxf((v.z - mean[2]) * scl[2] + bb[2], 0.f);
        a3 += fmaxf((v.w - mean[3]) * scl[3] + bb[3], 0.f);
    }
    atomicAdd(&pooled_sum[cur * F_HID + c4 + 0], a0);
    atomicAdd(&pooled_sum[cur * F_HID + c4 + 1], a1);
    atomicAdd(&pooled_sum[cur * F_HID + c4 + 2], a2);
    atomicAdd(&pooled_sum[cur * F_HID + c4 + 3], a3);
}

// ---------------- MLP head (boundary search + divide-by-count folded in) ----------------
__global__ __launch_bounds__(256) void mlp_kernel(const float* __restrict__ pooled_sum, const int* __restrict__ batch,
                                                  const float* __restrict__ Wf1, const float* __restrict__ bf1,
                                                  const float* __restrict__ Wf2, const float* __restrict__ bf2,
                                                  float* __restrict__ out) {
    __shared__ float p[128];
    __shared__ float h1[256];
    __shared__ int se[2];
    int g = blockIdx.x, t = threadIdx.x;
    if (t < 2) {   // lower_bound(batch, g + t)
        int target = g + t;
        int lo = 0, hi = N_NODES;
        while (lo < hi) {
            int mid = (lo + hi) >> 1;
            if (batch[mid] < target) lo = mid + 1; else hi = mid;
        }
        se[t] = lo;
    }
    __syncthreads();
    if (t < 128) {
        float cnt = (float)(se[1] - se[0]);
        p[t] = pooled_sum[g * F_HID + t] / fmaxf(cnt, 1.0f);
    }
    __syncthreads();
    float acc = bf1[t];
#pragma unroll 8
    for (int k = 0; k < 128; k++) acc = fmaf(p[k], Wf1[k * 256 + t], acc);
    h1[t] = fmaxf(acc, 0.f);
    __syncthreads();
    if (t < 10) {
        float o = bf2[t];
#pragma unroll 8
        for (int j = 0; j < 256; j++) o = fmaf(h1[j], Wf2[j * 10 + t], o);
        out[g * 10 + t] = o;
    }
}

// ---------------- host launch ----------------
extern "C" void kernel_launch(void* const* d_in, const int* in_sizes, int n_in,
                              void* d_out, int out_size, void* d_ws, size_t ws_size,
                              hipStream_t stream) {
    (void)in_sizes; (void)n_in; (void)out_size; (void)ws_size;
    const float* x     = (const float*)d_in[0];
    const int*   ei    = (const int*)d_in[1];
    const int*   batch = (const int*)d_in[2];
    const float* W1    = (const float*)d_in[3];
    const float* g1    = (const float*)d_in[5];
    const float* beta1 = (const float*)d_in[6];
    const float* W2    = (const float*)d_in[7];
    const float* g2    = (const float*)d_in[9];
    const float* beta2 = (const float*)d_in[10];
    const float* W3    = (const float*)d_in[11];
    const float* g3    = (const float*)d_in[13];
    const float* beta3 = (const float*)d_in[14];
    const float* Wf1   = (const float*)d_in[15];
    const float* bf1   = (const float*)d_in[16];
    const float* Wf2   = (const float*)d_in[17];
    const float* bf2   = (const float*)d_in[18];
    float* out = (float*)d_out;

    char* p = (char*)d_ws;
    auto alloc = [&](size_t bytes) { char* q = p; p += (bytes + 255) & ~(size_t)255; return q; };
    // --- zero-init region (one memset): cnt | col | colstats | pooled_sum ---
    char*   zbase     = p;
    int*    cnt       = (int*)   alloc((size_t)N_NODES * 4);
    uint*   col       = (uint*)  alloc((size_t)COL_MAX * 4);           // padded CSR records
    float*  colstats  = (float*) alloc(3 * 256 * 4);
    float*  pooled_sum= (float*) alloc((size_t)N_GRAPHS * F_HID * 4);
    size_t  zbytes    = (size_t)(p - zbase);
    // --- rest ---
    ushort* xb        = (ushort*)alloc((size_t)N_NODES * 96 * 2);
    ushort* hbA       = (ushort*)alloc((size_t)N_NODES * F_HID * 2);   // bf16 gemm out
    float*  bufF      = (float*) alloc((size_t)N_NODES * F_HID * 4);   // f32 agg out
    ushort* W1t       = (ushort*)alloc((size_t)96  * 128 * 2);
    ushort* W2t       = (ushort*)alloc((size_t)128 * 128 * 2);
    ushort* W3t       = (ushort*)alloc((size_t)128 * 128 * 2);
    int*    row_ptr   = (int*)   alloc((size_t)(N_NODES + 1) * 4);
    int*    cursor    = (int*)   alloc((size_t)N_NODES * 4);
    float*  dinv      = (float*) alloc((size_t)N_NODES * 4);
    int*    blockSums = (int*)   alloc(64 * 4);
    int*    blockOff  = (int*)   alloc(64 * 4);

    int nb = (N_NODES + 1023) / 1024;   // 49

    // 1. zero accumulators + col (pad records become src=0, w=fp16(0))
    hipMemsetAsync(zbase, 0, zbytes, stream);
    // 2. conversions + degree count (merged)
    prep_kernel<<<PREP_BLOCKS, 256, 0, stream>>>(x, ei, W1, W2, W3, xb, W1t, W2t, W3t, cnt);
    // 3-5. scan chain (padded row lengths)
    scan_blocks_kernel<<<nb, 1024, 0, stream>>>(cnt, row_ptr, blockSums);
    scan_totals_kernel<<<1, 64, 0, stream>>>(blockSums, blockOff, row_ptr, nb);
    finalize_kernel<<<(N_NODES + 255) / 256, 256, 0, stream>>>(row_ptr, blockOff, cnt, dinv, cursor);
    // 6. CSR fill overlapped with layer-1 GEMM
    fillgemm_kernel<<<GEMM1_BLOCKS + FILL_BLOCKS, 256, 0, stream>>>(ei, dinv, cursor, col, xb, W1t, hbA);
    // layer 1 rest
    aggregate_kernel<<<N_NODES / 4, 256, 0, stream>>>(hbA, row_ptr, col, bufF);
    stats_kernel<<<256, 256, 0, stream>>>(bufF, colstats);
    // layer 2
    mfma_gemm_bn_kernel<<<GEMM1_BLOCKS, 256, 0, stream>>>(bufF, colstats, g1, beta1, W2t, hbA);
    aggregate_kernel<<<N_NODES / 4, 256, 0, stream>>>(hbA, row_ptr, col, bufF);
    stats_kernel<<<256, 256, 0, stream>>>(bufF, colstats + 256);
    // layer 3
    mfma_gemm_bn_kernel<<<GEMM1_BLOCKS, 256, 0, stream>>>(bufF, colstats + 256, g2, beta2, W3t, hbA);
    aggregate_kernel<<<N_NODES / 4, 256, 0, stream>>>(hbA, row_ptr, col, bufF);
    stats_kernel<<<256, 256, 0, stream>>>(bufF, colstats + 512);
    // fused BN+ReLU+pool, then MLP head
    pool_bn_kernel<<<(N_NODES + POOL_ROWS - 1) / POOL_ROWS, 256, 0, stream>>>(bufF, colstats + 512, g3, beta3, batch, pooled_sum);
    mlp_kernel<<<N_GRAPHS, 256, 0, stream>>>(pooled_sum, batch, Wf1, bf1, Wf2, bf2, out);
}

// Round 7
// 448.360 us; speedup vs baseline: 1.5807x; 1.0110x over previous
//
#include <hip/hip_runtime.h>
#include <hip/hip_bf16.h>
#include <hip/hip_fp16.h>

// ---------------- problem constants (match reference) ----------------
constexpr int N_NODES  = 50000;
constexpr int N_EDGES  = 800000;
constexpr int NE_TOT   = N_EDGES + N_NODES;   // edges + self loops
constexpr int COL_MAX  = NE_TOT + 7 * N_NODES; // worst-case padded CSR records
constexpr int F_HID    = 128;
constexpr int N_GRAPHS = 64;
constexpr float BN_EPS = 1e-5f;

using short8  = __attribute__((ext_vector_type(8))) short;
using float4v = __attribute__((ext_vector_type(4))) float;

__device__ __forceinline__ ushort f2bf(float f) {
    uint u = __float_as_uint(f);
    return (ushort)((u + 0x7fffu + ((u >> 16) & 1u)) >> 16);   // RNE
}
__device__ __forceinline__ float bflo(uint u) { return __uint_as_float(u << 16); }
__device__ __forceinline__ float bfhi(uint u) { return __uint_as_float(u & 0xffff0000u); }

// ---------------- merged prep: conv_x | conv_w(all 3) | degree count ----------------
constexpr int CONVX_BLOCKS = (N_NODES * 96 / 4 + 255) / 256;           // 4688
constexpr int CONVW_ELEMS  = 96 * 128 + 2 * 128 * 128;                 // 45056
constexpr int CONVW_BLOCKS = (CONVW_ELEMS + 255) / 256;                // 176
constexpr int COUNT_BLOCKS = (N_EDGES + 255) / 256;                    // 3125
constexpr int PREP_BLOCKS  = CONVX_BLOCKS + CONVW_BLOCKS + COUNT_BLOCKS;

__global__ __launch_bounds__(256) void prep_kernel(const float* __restrict__ x, const int* __restrict__ ei,
                                                   const float* __restrict__ W1, const float* __restrict__ W2,
                                                   const float* __restrict__ W3, ushort* __restrict__ xb,
                                                   ushort* __restrict__ W1t, ushort* __restrict__ W2t,
                                                   ushort* __restrict__ W3t, int* __restrict__ cnt) {
    int b = blockIdx.x;
    if (b < CONVX_BLOCKS) {
        int i = b * 256 + threadIdx.x;
        constexpr int TOT4 = N_NODES * 96 / 4;
        if (i >= TOT4) return;
        float4 v = ((const float4*)x)[i];
        ushort4 o = {f2bf(v.x), f2bf(v.y), f2bf(v.z), f2bf(v.w)};
        ((ushort4*)xb)[i] = o;
    } else if (b < CONVX_BLOCKS + CONVW_BLOCKS) {
        int i = (b - CONVX_BLOCKS) * 256 + threadIdx.x;
        constexpr int S1 = 96 * 128, S2 = S1 + 128 * 128, S3 = S2 + 128 * 128;
        if (i < S1) {
            int n = i & 127, k = i >> 7;
            W1t[n * 96 + k] = f2bf(W1[i]);
        } else if (i < S2) {
            int j = i - S1, n = j & 127, k = j >> 7;
            W2t[n * 128 + k] = f2bf(W2[j]);
        } else if (i < S3) {
            int j = i - S2, n = j & 127, k = j >> 7;
            W3t[n * 128 + k] = f2bf(W3[j]);
        }
    } else {
        int i = (b - CONVX_BLOCKS - CONVW_BLOCKS) * 256 + threadIdx.x;
        if (i < N_EDGES) atomicAdd(&cnt[ei[N_EDGES + i]], 1);   // dst in-degree (cnt pre-zeroed)
    }
}

// ---------------- 3-phase exclusive scan over padded row lengths -> row_ptr ----------------
// row length = pad8(cnt[i] + 1)   (+1 self loop, padded to multiple of 8)
__global__ __launch_bounds__(1024) void scan_blocks_kernel(const int* __restrict__ cnt,
                                                           int* __restrict__ row_ptr,
                                                           int* __restrict__ blockSums) {
    int tid = threadIdx.x;
    int gid = blockIdx.x * 1024 + tid;
    int v = (gid < N_NODES) ? ((cnt[gid] + 8) & ~7) : 0;
    int lane = tid & 63, wid = tid >> 6;
    int x = v;
#pragma unroll
    for (int off = 1; off < 64; off <<= 1) {
        int y = __shfl_up(x, off);
        if (lane >= off) x += y;
    }
    __shared__ int wsum[16];
    if (lane == 63) wsum[wid] = x;
    __syncthreads();
    if (tid < 16) {
        int w = wsum[tid];
        int xx = w;
#pragma unroll
        for (int off = 1; off < 16; off <<= 1) {
            int y = __shfl_up(xx, off);
            if (tid >= off) xx += y;
        }
        wsum[tid] = xx - w;
    }
    __syncthreads();
    int incl = x + wsum[wid];
    if (gid < N_NODES) row_ptr[gid] = incl - v;
    if (tid == 1023) blockSums[blockIdx.x] = incl;
}

__global__ void scan_totals_kernel(const int* __restrict__ blockSums, int* __restrict__ blockOff,
                                   int* __restrict__ row_ptr, int nb) {
    int lane = threadIdx.x;   // single wave
    int v = (lane < nb) ? blockSums[lane] : 0;
    int x = v;
#pragma unroll
    for (int off = 1; off < 64; off <<= 1) {
        int y = __shfl_up(x, off);
        if (lane >= off) x += y;
    }
    if (lane < nb) blockOff[lane] = x - v;
    if (lane == nb - 1) row_ptr[N_NODES] = x;
}

__global__ __launch_bounds__(256) void finalize_kernel(int* __restrict__ row_ptr, const int* __restrict__ blockOff,
                                                       const int* __restrict__ cnt, float* __restrict__ dinv,
                                                       int* __restrict__ cursor) {
    int i = blockIdx.x * 256 + threadIdx.x;
    if (i >= N_NODES) return;
    int rp = row_ptr[i] + blockOff[i >> 10];
    row_ptr[i] = rp;
    cursor[i] = rp;
    dinv[i] = rsqrtf((float)(cnt[i] + 1));   // degree incl self loop
}

// ---------------- merged fill | layer-1 MFMA GEMM ----------------
constexpr int GEMM1_BLOCKS = (N_NODES + 63) / 64;       // 782
constexpr int FILL_BLOCKS  = (NE_TOT + 255) / 256;      // 3321

__global__ __launch_bounds__(256) void fillgemm_kernel(const int* __restrict__ ei, const float* __restrict__ dinv,
                                                       int* __restrict__ cursor, uint* __restrict__ col,
                                                       const ushort* __restrict__ A, const ushort* __restrict__ Wt,
                                                       ushort* __restrict__ C) {
    if (blockIdx.x < GEMM1_BLOCKS) {
        // ---- layer-1 GEMM: C[N,128] = A[N,96] @ W ----
        constexpr int K = 96, KSTEPS = 3;
        int wave = threadIdx.x >> 6, lane = threadIdx.x & 63;
        int m = lane & 15, quad = lane >> 4;
        int row_base = blockIdx.x * 64 + wave * 16;
        short8 afrag[KSTEPS];
        int arow = min(row_base + m, N_NODES - 1);
#pragma unroll
        for (int ks = 0; ks < KSTEPS; ks++)
            afrag[ks] = *(const short8*)(A + (size_t)arow * K + ks * 32 + quad * 8);
#pragma unroll
        for (int nt = 0; nt < 8; nt++) {
            float4v acc = {0.f, 0.f, 0.f, 0.f};
            const ushort* wbase = Wt + (size_t)(nt * 16 + m) * K + quad * 8;
#pragma unroll
            for (int ks = 0; ks < KSTEPS; ks++) {
                short8 bfrag = *(const short8*)(wbase + ks * 32);
                acc = __builtin_amdgcn_mfma_f32_16x16x32_bf16(afrag[ks], bfrag, acc, 0, 0, 0);
            }
            int colg = nt * 16 + m;
#pragma unroll
            for (int r = 0; r < 4; r++) {
                int rowg = row_base + quad * 4 + r;
                if (rowg < N_NODES) C[(size_t)rowg * F_HID + colg] = f2bf(acc[r]);
            }
        }
    } else {
        // ---- CSR fill: packed record (fp16 norm | u16 src) ----
        int i = (blockIdx.x - GEMM1_BLOCKS) * 256 + threadIdx.x;
        if (i >= NE_TOT) return;
        int s, d;
        if (i < N_EDGES) { s = ei[i]; d = ei[N_EDGES + i]; }
        else             { s = i - N_EDGES; d = s; }
        int pos = atomicAdd(&cursor[d], 1);
        float nrm = dinv[s] * dinv[d];
        uint h16 = (uint)__half_as_ushort(__float2half(nrm));
        col[pos] = (h16 << 16) | (uint)s;
    }
}

// ---------------- MFMA transform with fused BN+ReLU on A (layers 2,3), bf16 in/out ----------------
__global__ __launch_bounds__(256) void mfma_gemm_bn_kernel(const ushort* __restrict__ A, const float* __restrict__ cs,
                                                           const float* __restrict__ gam, const float* __restrict__ bet,
                                                           const ushort* __restrict__ Wt, ushort* __restrict__ C) {
    constexpr int K = 128, KSTEPS = 4;
    int wave = threadIdx.x >> 6, lane = threadIdx.x & 63;
    int m = lane & 15, quad = lane >> 4;
    int row_base = blockIdx.x * 64 + wave * 16;
    int arow = min(row_base + m, N_NODES - 1);
    constexpr float invN = 1.0f / N_NODES;

    short8 afrag[KSTEPS];
#pragma unroll
    for (int ks = 0; ks < KSTEPS; ks++) {
        int k0 = ks * 32 + quad * 8;
        uint4 av = *(const uint4*)(A + (size_t)arow * K + k0);   // 8 bf16
        float vals[8] = {bflo(av.x), bfhi(av.x), bflo(av.y), bfhi(av.y),
                         bflo(av.z), bfhi(av.z), bflo(av.w), bfhi(av.w)};
#pragma unroll
        for (int jj = 0; jj < 8; jj += 4) {
            float4 sv = *(const float4*)(cs + k0 + jj);
            float4 qv = *(const float4*)(cs + 128 + k0 + jj);
            float4 gv = *(const float4*)(gam + k0 + jj);
            float4 bv = *(const float4*)(bet + k0 + jj);
            const float* s = (const float*)&sv; const float* q = (const float*)&qv;
            const float* g = (const float*)&gv; const float* b = (const float*)&bv;
#pragma unroll
            for (int t = 0; t < 4; t++) {
                float mean = s[t] * invN;
                float var  = q[t] * invN - mean * mean;
                float sc   = g[t] * rsqrtf(var + BN_EPS);
                float val  = fmaxf((vals[jj + t] - mean) * sc + b[t], 0.0f);
                afrag[ks][jj + t] = (short)f2bf(val);
            }
        }
    }

#pragma unroll
    for (int nt = 0; nt < 8; nt++) {
        float4v acc = {0.f, 0.f, 0.f, 0.f};
        const ushort* wbase = Wt + (size_t)(nt * 16 + m) * K + quad * 8;
#pragma unroll
        for (int ks = 0; ks < KSTEPS; ks++) {
            short8 bfrag = *(const short8*)(wbase + ks * 32);
            acc = __builtin_amdgcn_mfma_f32_16x16x32_bf16(afrag[ks], bfrag, acc, 0, 0, 0);
        }
        int colg = nt * 16 + m;
#pragma unroll
        for (int r = 0; r < 4; r++) {
            int rowg = row_base + quad * 4 + r;
            if (rowg < N_NODES) C[(size_t)rowg * F_HID + colg] = f2bf(acc[r]);
        }
    }
}

// ---------------- sparse aggregation: one wave per dst row, quarter-wave gathers ----------------
// each quarter (16 lanes) serves one edge; lane covers cols sl*8..sl*8+7 (uint4 = 8 bf16)
// rows padded to x8 with zero records (src=0, w=0). bf16 out.
__global__ __launch_bounds__(256) void aggregate_kernel(const ushort* __restrict__ h, const int* __restrict__ row_ptr,
                                                        const uint* __restrict__ col, ushort* __restrict__ outp) {
    int wv   = (blockIdx.x * 256 + threadIdx.x) >> 6;
    int lane = threadIdx.x & 63;
    if (wv >= N_NODES) return;
    int q  = lane >> 4;     // 0..3 edge slot
    int sl = lane & 15;     // col group
    int beg = row_ptr[wv], end = row_ptr[wv + 1];
    float a0 = 0, a1 = 0, a2 = 0, a3 = 0, a4 = 0, a5 = 0, a6 = 0, a7 = 0;
    int base = beg;
    for (; base + 16 <= end; base += 16) {   // 16 edges per iteration, 4 gathers in flight per lane
        uint r0 = col[base + q];
        uint r1 = col[base + 4 + q];
        uint r2 = col[base + 8 + q];
        uint r3 = col[base + 12 + q];
        uint4 v0 = *(const uint4*)(h + (size_t)(r0 & 0xFFFFu) * F_HID + sl * 8);
        uint4 v1 = *(const uint4*)(h + (size_t)(r1 & 0xFFFFu) * F_HID + sl * 8);
        uint4 v2 = *(const uint4*)(h + (size_t)(r2 & 0xFFFFu) * F_HID + sl * 8);
        uint4 v3 = *(const uint4*)(h + (size_t)(r3 & 0xFFFFu) * F_HID + sl * 8);
        float w0 = __half2float(__ushort_as_half((ushort)(r0 >> 16)));
        float w1 = __half2float(__ushort_as_half((ushort)(r1 >> 16)));
        float w2 = __half2float(__ushort_as_half((ushort)(r2 >> 16)));
        float w3 = __half2float(__ushort_as_half((ushort)(r3 >> 16)));
        a0 += w0 * bflo(v0.x); a1 += w0 * bfhi(v0.x); a2 += w0 * bflo(v0.y); a3 += w0 * bfhi(v0.y);
        a4 += w0 * bflo(v0.z); a5 += w0 * bfhi(v0.z); a6 += w0 * bflo(v0.w); a7 += w0 * bfhi(v0.w);
        a0 += w1 * bflo(v1.x); a1 += w1 * bfhi(v1.x); a2 += w1 * bflo(v1.y); a3 += w1 * bfhi(v1.y);
        a4 += w1 * bflo(v1.z); a5 += w1 * bfhi(v1.z); a6 += w1 * bflo(v1.w); a7 += w1 * bfhi(v1.w);
        a0 += w2 * bflo(v2.x); a1 += w2 * bfhi(v2.x); a2 += w2 * bflo(v2.y); a3 += w2 * bfhi(v2.y);
        a4 += w2 * bflo(v2.z); a5 += w2 * bfhi(v2.z); a6 += w2 * bflo(v2.w); a7 += w2 * bfhi(v2.w);
        a0 += w3 * bflo(v3.x); a1 += w3 * bfhi(v3.x); a2 += w3 * bflo(v3.y); a3 += w3 * bfhi(v3.y);
        a4 += w3 * bflo(v3.z); a5 += w3 * bfhi(v3.z); a6 += w3 * bflo(v3.w); a7 += w3 * bfhi(v3.w);
    }
    if (base < end) {   // exactly 8 remain (row length % 8 == 0)
        uint r0 = col[base + q];
        uint r1 = col[base + 4 + q];
        uint4 v0 = *(const uint4*)(h + (size_t)(r0 & 0xFFFFu) * F_HID + sl * 8);
        uint4 v1 = *(const uint4*)(h + (size_t)(r1 & 0xFFFFu) * F_HID + sl * 8);
        float w0 = __half2float(__ushort_as_half((ushort)(r0 >> 16)));
        float w1 = __half2float(__ushort_as_half((ushort)(r1 >> 16)));
        a0 += w0 * bflo(v0.x); a1 += w0 * bfhi(v0.x); a2 += w0 * bflo(v0.y); a3 += w0 * bfhi(v0.y);
        a4 += w0 * bflo(v0.z); a5 += w0 * bfhi(v0.z); a6 += w0 * bflo(v0.w); a7 += w0 * bfhi(v0.w);
        a0 += w1 * bflo(v1.x); a1 += w1 * bfhi(v1.x); a2 += w1 * bflo(v1.y); a3 += w1 * bfhi(v1.y);
        a4 += w1 * bflo(v1.z); a5 += w1 * bfhi(v1.z); a6 += w1 * bflo(v1.w); a7 += w1 * bfhi(v1.w);
    }
    // combine quarters: +16 then +32
    a0 += __shfl_down(a0, 16); a1 += __shfl_down(a1, 16); a2 += __shfl_down(a2, 16); a3 += __shfl_down(a3, 16);
    a4 += __shfl_down(a4, 16); a5 += __shfl_down(a5, 16); a6 += __shfl_down(a6, 16); a7 += __shfl_down(a7, 16);
    a0 += __shfl_down(a0, 32); a1 += __shfl_down(a1, 32); a2 += __shfl_down(a2, 32); a3 += __shfl_down(a3, 32);
    a4 += __shfl_down(a4, 32); a5 += __shfl_down(a5, 32); a6 += __shfl_down(a6, 32); a7 += __shfl_down(a7, 32);
    if (q == 0) {
        uint4 o;
        o.x = (uint)f2bf(a0) | ((uint)f2bf(a1) << 16);
        o.y = (uint)f2bf(a2) | ((uint)f2bf(a3) << 16);
        o.z = (uint)f2bf(a4) | ((uint)f2bf(a5) << 16);
        o.w = (uint)f2bf(a6) | ((uint)f2bf(a7) << 16);
        *(uint4*)(outp + (size_t)wv * F_HID + sl * 8) = o;
    }
}

// ---------------- BN stats (column sums / sumsq over bf16 agg) ----------------
__global__ __launch_bounds__(256) void stats_kernel(const ushort* __restrict__ h, float* __restrict__ colstats) {
    int c4 = (threadIdx.x & 31) * 4;
    int stripe = threadIdx.x >> 5;   // 0..7
    float s0 = 0, s1 = 0, s2 = 0, s3 = 0, q0 = 0, q1 = 0, q2 = 0, q3 = 0;
    for (int n = blockIdx.x * 8 + stripe; n < N_NODES; n += gridDim.x * 8) {
        uint2 v = *(const uint2*)(h + (size_t)n * F_HID + c4);
        float x0 = bflo(v.x), x1 = bfhi(v.x), x2 = bflo(v.y), x3 = bfhi(v.y);
        s0 += x0; s1 += x1; s2 += x2; s3 += x3;
        q0 += x0 * x0; q1 += x1 * x1; q2 += x2 * x2; q3 += x3 * x3;
    }
    __shared__ float sh[8][256];
    sh[0][threadIdx.x] = s0; sh[1][threadIdx.x] = s1; sh[2][threadIdx.x] = s2; sh[3][threadIdx.x] = s3;
    sh[4][threadIdx.x] = q0; sh[5][threadIdx.x] = q1; sh[6][threadIdx.x] = q2; sh[7][threadIdx.x] = q3;
    __syncthreads();
    if (stripe == 0) {
        int t = threadIdx.x;
#pragma unroll
        for (int c = 0; c < 4; c++) {
            float ts = 0, tq = 0;
#pragma unroll
            for (int k = 0; k < 8; k++) { ts += sh[c][k * 32 + t]; tq += sh[4 + c][k * 32 + t]; }
            atomicAdd(&colstats[c4 + c],       ts);
            atomicAdd(&colstats[128 + c4 + c], tq);
        }
    }
}

// ---------------- fused layer-3 BN+ReLU + graph pooling (bf16 in) ----------------
constexpr int POOL_ROWS = 128;
__global__ __launch_bounds__(256) void pool_bn_kernel(const ushort* __restrict__ h, const float* __restrict__ cs,
                                                      const float* __restrict__ gam, const float* __restrict__ bet,
                                                      const int* __restrict__ batch, float* __restrict__ pooled_sum) {
    int row0 = blockIdx.x * POOL_ROWS;
    int c4 = (threadIdx.x & 31) * 4;
    int stripe = threadIdx.x >> 5;   // 0..7
    __shared__ int sbatch[POOL_ROWS];
    if (threadIdx.x < POOL_ROWS) {
        int r = row0 + threadIdx.x;
        sbatch[threadIdx.x] = (r < N_NODES) ? batch[r] : -1;
    }
    __syncthreads();
    int nrows = min(POOL_ROWS, N_NODES - row0);
    if (stripe >= nrows) return;
    constexpr float invN = 1.0f / N_NODES;
    float mean[4], scl[4], bb[4];
#pragma unroll
    for (int t = 0; t < 4; t++) {
        float mn = cs[c4 + t] * invN;
        float var = cs[128 + c4 + t] * invN - mn * mn;
        mean[t] = mn;
        scl[t] = gam[c4 + t] * rsqrtf(var + BN_EPS);
        bb[t] = bet[c4 + t];
    }
    int cur = sbatch[stripe];
    float a0 = 0, a1 = 0, a2 = 0, a3 = 0;
    for (int r = stripe; r < nrows; r += 8) {
        int g = sbatch[r];
        if (g != cur) {
            atomicAdd(&pooled_sum[cur * F_HID + c4 + 0], a0);
            atomicAdd(&pooled_sum[cur * F_HID + c4 + 1], a1);
            atomicAdd(&pooled_sum[cur * F_HID + c4 + 2], a2);
            atomicAdd(&pooled_sum[cur * F_HID + c4 + 3], a3);
            cur = g; a0 = a1 = a2 = a3 = 0.f;
        }
        uint2 v = *(const uint2*)(h + (size_t)(row0 + r) * F_HID + c4);
        a0 += fmaxf((bflo(v.x) - mean[0]) * scl[0] + bb[0], 0.f);
        a1 += fmaxf((bfhi(v.x) - mean[1]) * scl[1] + bb[1], 0.f);
        a2 += fmaxf((bflo(v.y) - mean[2]) * scl[2] + bb[2], 0.f);
        a3 += fmaxf((bfhi(v.y) - mean[3]) * scl[3] + bb[3], 0.f);
    }
    atomicAdd(&pooled_sum[cur * F_HID + c4 + 0], a0);
    atomicAdd(&pooled_sum[cur * F_HID + c4 + 1], a1);
    atomicAdd(&pooled_sum[cur * F_HID + c4 + 2], a2);
    atomicAdd(&pooled_sum[cur * F_HID + c4 + 3], a3);
}

// ---------------- MLP head (boundary search + divide-by-count folded in) ----------------
__global__ __launch_bounds__(256) void mlp_kernel(const float* __restrict__ pooled_sum, const int* __restrict__ batch,
                                                  const float* __restrict__ Wf1, const float* __restrict__ bf1,
                                                  const float* __restrict__ Wf2, const float* __restrict__ bf2,
                                                  float* __restrict__ out) {
    __shared__ float p[128];
    __shared__ float h1[256];
    __shared__ int se[2];
    int g = blockIdx.x, t = threadIdx.x;
    if (t < 2) {   // lower_bound(batch, g + t)
        int target = g + t;
        int lo = 0, hi = N_NODES;
        while (lo < hi) {
            int mid = (lo + hi) >> 1;
            if (batch[mid] < target) lo = mid + 1; else hi = mid;
        }
        se[t] = lo;
    }
    __syncthreads();
    if (t < 128) {
        float cnt = (float)(se[1] - se[0]);
        p[t] = pooled_sum[g * F_HID + t] / fmaxf(cnt, 1.0f);
    }
    __syncthreads();
    float acc = bf1[t];
#pragma unroll 8
    for (int k = 0; k < 128; k++) acc = fmaf(p[k], Wf1[k * 256 + t], acc);
    h1[t] = fmaxf(acc, 0.f);
    __syncthreads();
    if (t < 10) {
        float o = bf2[t];
#pragma unroll 8
        for (int j = 0; j < 256; j++) o = fmaf(h1[j], Wf2[j * 10 + t], o);
        out[g * 10 + t] = o;
    }
}

// ---------------- host launch ----------------
extern "C" void kernel_launch(void* const* d_in, const int* in_sizes, int n_in,
                              void* d_out, int out_size, void* d_ws, size_t ws_size,
                              hipStream_t stream) {
    (void)in_sizes; (void)n_in; (void)out_size; (void)ws_size;
    const float* x     = (const float*)d_in[0];
    const int*   ei    = (const int*)d_in[1];
    const int*   batch = (const int*)d_in[2];
    const float* W1    = (const float*)d_in[3];
    const float* g1    = (const float*)d_in[5];
    const float* beta1 = (const float*)d_in[6];
    const float* W2    = (const float*)d_in[7];
    const float* g2    = (const float*)d_in[9];
    const float* beta2 = (const float*)d_in[10];
    const float* W3    = (const float*)d_in[11];
    const float* g3    = (const float*)d_in[13];
    const float* beta3 = (const float*)d_in[14];
    const float* Wf1   = (const float*)d_in[15];
    const float* bf1   = (const float*)d_in[16];
    const float* Wf2   = (const float*)d_in[17];
    const float* bf2   = (const float*)d_in[18];
    float* out = (float*)d_out;

    char* p = (char*)d_ws;
    auto alloc = [&](size_t bytes) { char* q = p; p += (bytes + 255) & ~(size_t)255; return q; };
    // --- zero-init region (one memset): cnt | col | colstats | pooled_sum ---
    char*   zbase     = p;
    int*    cnt       = (int*)   alloc((size_t)N_NODES * 4);
    uint*   col       = (uint*)  alloc((size_t)COL_MAX * 4);           // padded CSR records
    float*  colstats  = (float*) alloc(3 * 256 * 4);
    float*  pooled_sum= (float*) alloc((size_t)N_GRAPHS * F_HID * 4);
    size_t  zbytes    = (size_t)(p - zbase);
    // --- rest ---
    ushort* xb        = (ushort*)alloc((size_t)N_NODES * 96 * 2);
    ushort* hbA       = (ushort*)alloc((size_t)N_NODES * F_HID * 2);   // bf16 gemm out
    ushort* hbB       = (ushort*)alloc((size_t)N_NODES * F_HID * 2);   // bf16 agg out
    ushort* W1t       = (ushort*)alloc((size_t)96  * 128 * 2);
    ushort* W2t       = (ushort*)alloc((size_t)128 * 128 * 2);
    ushort* W3t       = (ushort*)alloc((size_t)128 * 128 * 2);
    int*    row_ptr   = (int*)   alloc((size_t)(N_NODES + 1) * 4);
    int*    cursor    = (int*)   alloc((size_t)N_NODES * 4);
    float*  dinv      = (float*) alloc((size_t)N_NODES * 4);
    int*    blockSums = (int*)   alloc(64 * 4);
    int*    blockOff  = (int*)   alloc(64 * 4);

    int nb = (N_NODES + 1023) / 1024;   // 49

    // 1. zero accumulators + col (pad records become src=0, w=fp16(0))
    hipMemsetAsync(zbase, 0, zbytes, stream);
    // 2. conversions + degree count (merged)
    prep_kernel<<<PREP_BLOCKS, 256, 0, stream>>>(x, ei, W1, W2, W3, xb, W1t, W2t, W3t, cnt);
    // 3-5. scan chain (padded row lengths)
    scan_blocks_kernel<<<nb, 1024, 0, stream>>>(cnt, row_ptr, blockSums);
    scan_totals_kernel<<<1, 64, 0, stream>>>(blockSums, blockOff, row_ptr, nb);
    finalize_kernel<<<(N_NODES + 255) / 256, 256, 0, stream>>>(row_ptr, blockOff, cnt, dinv, cursor);
    // 6. CSR fill overlapped with layer-1 GEMM
    fillgemm_kernel<<<GEMM1_BLOCKS + FILL_BLOCKS, 256, 0, stream>>>(ei, dinv, cursor, col, xb, W1t, hbA);
    // layer 1 rest
    aggregate_kernel<<<N_NODES / 4, 256, 0, stream>>>(hbA, row_ptr, col, hbB);
    stats_kernel<<<256, 256, 0, stream>>>(hbB, colstats);
    // layer 2
    mfma_gemm_bn_kernel<<<GEMM1_BLOCKS, 256, 0, stream>>>(hbB, colstats, g1, beta1, W2t, hbA);
    aggregate_kernel<<<N_NODES / 4, 256, 0, stream>>>(hbA, row_ptr, col, hbB);
    stats_kernel<<<256, 256, 0, stream>>>(hbB, colstats + 256);
    // layer 3
    mfma_gemm_bn_kernel<<<GEMM1_BLOCKS, 256, 0, stream>>>(hbB, colstats + 256, g2, beta2, W3t, hbA);
    aggregate_kernel<<<N_NODES / 4, 256, 0, stream>>>(hbA, row_ptr, col, hbB);
    stats_kernel<<<256, 256, 0, stream>>>(hbB, colstats + 512);
    // fused BN+ReLU+pool, then MLP head
    pool_bn_kernel<<<(N_NODES + POOL_ROWS - 1) / POOL_ROWS, 256, 0, stream>>>(hbB, colstats + 512, g3, beta3, batch, pooled_sum);
    mlp_kernel<<<N_GRAPHS, 256, 0, stream>>>(pooled_sum, batch, Wf1, bf1, Wf2, bf2, out);
}